// Round 10
// baseline (348.883 us; speedup 1.0000x reference)
//
#include <hip/hip_runtime.h>
#include <hip/hip_bf16.h>

namespace {

constexpr int T = 8, HW = 196;
constexpr int C = 768, NH = 8, HD = 96;
constexpr int NTOK = 1568;
constexpr int BHT = 1024;          // B*NH*T
constexpr int C3 = 2304;           // 3*C
constexpr int CHW = HD * HW;       // 18816
constexpr int NROWS = 25088;       // B*NTOK
constexpr int NT = 13;             // 16-row tiles covering 208 >= 196
constexpr int KW = 104;            // Klds row stride (bf16)
constexpr int VW2 = 212;           // Vt row stride (bf16)
constexpr int UW = 72;             // corrT row stride
constexpr int TSZ = 128 * 64;      // one GEMM LDS tile (elems)

using bf16 = __hip_bfloat16;
typedef __attribute__((ext_vector_type(8))) short short8v;  // 8 x bf16 frag
typedef __attribute__((ext_vector_type(4))) float f32x4;

__device__ __forceinline__ float b2f(bf16 h) { return __bfloat162float(h); }
__device__ __forceinline__ bf16 f2b(float f) { return __float2bfloat16(f); }
__device__ __forceinline__ float u2f(ushort u) {
  union { ushort u[2]; float f; } x; x.u[0] = 0; x.u[1] = u; return x.f;
}
__device__ __forceinline__ ushort b2u(bf16 h) { union { bf16 b; ushort u; } x; x.b = h; return x.u; }
__device__ __forceinline__ uint pk2(float lo, float hi) {
  return ((uint)b2u(f2b(hi)) << 16) | (uint)b2u(f2b(lo));
}
__device__ __forceinline__ void gload_lds16(const bf16* g, bf16* l) {
  __builtin_amdgcn_global_load_lds(
      (const __attribute__((address_space(1))) unsigned int*)g,
      (__attribute__((address_space(3))) unsigned int*)l, 16, 0, 0);
}

// ---------------------------------------------------------------------------
// K0a: elementwise f32 -> bf16 (8 elems / thread)
// ---------------------------------------------------------------------------
__global__ __launch_bounds__(256) void conv_to_bf16(
    const float* __restrict__ X, bf16* __restrict__ Y, int n8) {
  const int i = blockIdx.x * 256 + threadIdx.x;
  if (i >= n8) return;
  const float4 a = ((const float4*)X)[i * 2];
  const float4 b = ((const float4*)X)[i * 2 + 1];
  uint4 o;
  o.x = pk2(a.x, a.y); o.y = pk2(a.z, a.w);
  o.z = pk2(b.x, b.y); o.w = pk2(b.z, b.w);
  ((uint4*)Y)[i] = o;
}

// ---------------------------------------------------------------------------
// K0b: W [rows][cols] f32 -> Wt [cols][rows] bf16, 64x64 LDS tiles.
// ---------------------------------------------------------------------------
__global__ __launch_bounds__(256) void transpose_to_bf16(
    const float* __restrict__ W, bf16* __restrict__ Wt, int rows, int cols) {
  __shared__ __align__(16) bf16 Lt[64][72];
  const int r0 = blockIdx.y * 64, c0 = blockIdx.x * 64;
  const int tid = threadIdx.x;
  const int r = tid >> 2, q = (tid & 3) * 16;
  const float* src = W + (size_t)(r0 + r) * cols + c0 + q;
#pragma unroll
  for (int i = 0; i < 16; i += 4) {
    const float4 v = *(const float4*)(src + i);
    Lt[q + i + 0][r] = f2b(v.x);
    Lt[q + i + 1][r] = f2b(v.y);
    Lt[q + i + 2][r] = f2b(v.z);
    Lt[q + i + 3][r] = f2b(v.w);
  }
  __syncthreads();
  const int c = tid >> 2, kc = (tid & 3) * 16;
  uint4* dst = (uint4*)(Wt + (size_t)(c0 + c) * rows + r0 + kc);
  const uint4* srcl = (const uint4*)(&Lt[c][kc]);
  dst[0] = srcl[0];
  dst[1] = srcl[1];
}

// ---------------------------------------------------------------------------
// Shared 128x128xK=768 MFMA core, double-buffered (T3 minimum-2-phase):
// STAGE(t+1 into buf^1) issued BEFORE MFMA(buf); one barrier per K-step
// (its vmcnt/lgkm drain is exactly the required hand-off semantics).
// ---------------------------------------------------------------------------
__device__ __forceinline__ void gemm128_core(
    const bf16* __restrict__ A, const bf16* __restrict__ Bt,
    int rt, int ct, bf16* As, bf16* Bs, f32x4 acc[4][4]) {
  const int tid = threadIdx.x;
  const int w = tid >> 6, lane = tid & 63;
  const int lr = lane & 15, lg = lane >> 4;
  const int wr = w >> 1, wc = w & 1;
  const int crow = (lane >> 3);
  const int cole = (lane & 7) * 8;
#pragma unroll
  for (int i = 0; i < 4; ++i)
#pragma unroll
    for (int j = 0; j < 4; ++j) acc[i][j] = (f32x4){0.f, 0.f, 0.f, 0.f};

#define STAGE_T(kt, dA, dB)                                                   \
  {                                                                           \
    const int k0s = (kt) * 64;                                                \
    _Pragma("unroll") for (int i = 0; i < 4; ++i) {                           \
      const int chunk = w * 4 + i;                                            \
      const int row = chunk * 8 + crow;                                       \
      gload_lds16(A + (size_t)(rt + row) * 768 + k0s + cole, (dA) + chunk * 512); \
      gload_lds16(Bt + (size_t)(ct + row) * 768 + k0s + cole, (dB) + chunk * 512); \
    }                                                                         \
  }

  STAGE_T(0, As, Bs);
  __syncthreads();
#pragma unroll
  for (int kt = 0; kt < 12; ++kt) {
    const int cur = (kt & 1) * TSZ;
    const int nxt = ((kt + 1) & 1) * TSZ;
    if (kt + 1 < 12) STAGE_T(kt + 1, As + nxt, Bs + nxt);
#pragma unroll
    for (int kc = 0; kc < 2; ++kc) {
      short8v xa[4], wb[4];
#pragma unroll
      for (int f = 0; f < 4; ++f) {
        xa[f] = *(const short8v*)(As + cur + (wr * 64 + f * 16 + lr) * 64 + kc * 32 + lg * 8);
        wb[f] = *(const short8v*)(Bs + cur + (wc * 64 + f * 16 + lr) * 64 + kc * 32 + lg * 8);
      }
#pragma unroll
      for (int cj = 0; cj < 4; ++cj)
#pragma unroll
        for (int ri = 0; ri < 4; ++ri)
          acc[cj][ri] = __builtin_amdgcn_mfma_f32_16x16x32_bf16(wb[cj], xa[ri], acc[cj][ri], 0, 0, 0);
    }
    __syncthreads();   // drains vmcnt(0): next tile landed; lgkm: reads done
  }
#undef STAGE_T
}

// ---------------------------------------------------------------------------
// K1: QKV GEMM, scatter epilogue to Q / K(shifted) / V (all unnormalized).
// ---------------------------------------------------------------------------
__global__ __launch_bounds__(256) void gemm_qkv_mfma(
    const bf16* __restrict__ A, const bf16* __restrict__ Bt,
    bf16* __restrict__ Qo, bf16* __restrict__ Ko, bf16* __restrict__ Vo) {
  __shared__ __align__(16) bf16 As[2 * TSZ];
  __shared__ __align__(16) bf16 Bs[2 * TSZ];
  const int id = blockIdx.x;
  const int sw = (id & 7) * 441 + (id >> 3);   // 3528 = 8 * 441 (bijective)
  const int cti = sw % 18, rti = sw / 18;
  const int ct = cti * 128, rt = rti * 128;
  const int tid = threadIdx.x;
  const int w = tid >> 6, lane = tid & 63;
  const int lr = lane & 15, lg = lane >> 4;
  const int wr = w >> 1, wc = w & 1;

  f32x4 acc[4][4];
  gemm128_core(A, Bt, rt, ct, As, Bs, acc);

  const int s = cti / 6;
#pragma unroll
  for (int ri = 0; ri < 4; ++ri) {
    const int row = rt + wr * 64 + ri * 16 + lr;
    const int b_ = row / NTOK, n = row % NTOK;
    const int t = n / HW, hw = n % HW;
#pragma unroll
    for (int cj = 0; cj < 4; ++cj) {
      const int colb = ct + wc * 64 + cj * 16 + lg * 4;
      const int rem = colb - s * C;
      const int head = rem / HD, chb = rem - head * HD;
      const int bh = b_ * NH + head;
      if (s == 0) {
        uint2 pk;
        pk.x = pk2(acc[cj][ri][0], acc[cj][ri][1]);
        pk.y = pk2(acc[cj][ri][2], acc[cj][ri][3]);
        *(uint2*)(Qo + (size_t)(bh * T + t) * CHW + hw * HD + chb) = pk;
      } else if (s == 1) {
        uint2 pk;
        pk.x = pk2(acc[cj][ri][0], acc[cj][ri][1]);
        pk.y = pk2(acc[cj][ri][2], acc[cj][ri][3]);
        if (t >= 1)
          *(uint2*)(Ko + (size_t)(bh * T + t - 1) * CHW + hw * HD + chb) = pk;
        if (t == T - 1)
          *(uint2*)(Ko + (size_t)(bh * T + t) * CHW + hw * HD + chb) = pk;
      } else {
#pragma unroll
        for (int j = 0; j < 4; ++j)
          Vo[(size_t)(bh * T + t) * CHW + (chb + j) * HW + hw] = f2b(acc[cj][ri][j]);
      }
    }
  }
}

// ---------------------------------------------------------------------------
// K4: proj GEMM + bias -> out f32.
// ---------------------------------------------------------------------------
__global__ __launch_bounds__(256) void gemm_proj_mfma(
    const bf16* __restrict__ A, const bf16* __restrict__ Bt,
    const float* __restrict__ bias, float* __restrict__ out) {
  __shared__ __align__(16) bf16 As[2 * TSZ];
  __shared__ __align__(16) bf16 Bs[2 * TSZ];
  const int id = blockIdx.x;
  const int sw = (id & 7) * 147 + (id >> 3);   // 1176 = 8 * 147 (bijective)
  const int cti = sw % 6, rti = sw / 6;
  const int ct = cti * 128, rt = rti * 128;
  const int tid = threadIdx.x;
  const int w = tid >> 6, lane = tid & 63;
  const int lr = lane & 15, lg = lane >> 4;
  const int wr = w >> 1, wc = w & 1;

  f32x4 acc[4][4];
  gemm128_core(A, Bt, rt, ct, As, Bs, acc);

#pragma unroll
  for (int ri = 0; ri < 4; ++ri) {
    const int row = rt + wr * 64 + ri * 16 + lr;
#pragma unroll
    for (int cj = 0; cj < 4; ++cj) {
      const int colb = ct + wc * 64 + cj * 16 + lg * 4;
      const float4 bv = *(const float4*)(bias + colb);
      float4 o;
      o.x = acc[cj][ri][0] + bv.x;
      o.y = acc[cj][ri][1] + bv.y;
      o.z = acc[cj][ri][2] + bv.z;
      o.w = acc[cj][ri][3] + bv.w;
      *(float4*)(out + (size_t)row * C + colb) = o;
    }
  }
}

// ---------------------------------------------------------------------------
// K3: fused l2norm + corr + appearance + motion attention per bt.
// 1024 threads, 16 waves, one 16-row tile per wave (4 waves/SIMD).
// ---------------------------------------------------------------------------
__global__ __launch_bounds__(1024, 1) void fused_attn(
    const bf16* __restrict__ Qg, const bf16* __restrict__ Kg,
    const bf16* __restrict__ Vg, const float* __restrict__ pos,
    bf16* __restrict__ merged) {
  __shared__ __align__(16) bf16 Klds[208 * KW];    // 43,264 B  K tokens x ch
  __shared__ __align__(16) bf16 Vt[96 * VW2];      // 40,704 B  V^T: ch x tok
  __shared__ __align__(16) bf16 corrT[208 * UW];   // 29,952 B  tok x disp(64pad)
  __shared__ float invQ[208];                      //     832 B
  const int bt = blockIdx.x;
  const int tid = threadIdx.x;
  const int w = tid >> 6, lane = tid & 63;
  const int lr = lane & 15, lg = lane >> 4;
  const size_t gbase = (size_t)bt * CHW;

  // ---- P0: staging + invQ ----
  {
    const uint4* kg = (const uint4*)(Kg + gbase);             // 196 rows x 12
    uint4* kl = (uint4*)Klds;                                 // 13 uint4/row
    for (int i = tid; i < 196 * 12; i += 1024) { const int r = i / 12, g = i - r * 12; kl[r * 13 + g] = kg[i]; }
    const uint4 z4 = make_uint4(0u, 0u, 0u, 0u);
    for (int i = tid; i < 12 * 13; i += 1024) { const int r = 196 + i / 13, g = i % 13; kl[r * 13 + g] = z4; }
    const uint* vg = (const uint*)(Vg + gbase);               // 96 x 98 u32
    uint* vl = (uint*)Vt;                                     // 106 u32/row
    for (int i = tid; i < 96 * 98; i += 1024) { const int c = i / 98, g = i - c * 98; vl[c * 106 + g] = vg[i]; }
    for (int i = tid; i < 96 * 8; i += 1024)  { const int c = i / 8, g = 98 + (i & 7); vl[c * 106 + g] = 0u; }
    uint* ct32 = (uint*)corrT;                                // 36 u32/row
    for (int i = tid; i < 208 * 36; i += 1024) {
      const int n = i % 208, up = i / 208;
      const int u0 = 2 * up, u1 = u0 + 1;
      const float p0 = (n < 196 && u0 < 49) ? pos[u0 * 196 + n] : 0.f;
      const float p1 = (n < 196 && u1 < 49) ? pos[u1 * 196 + n] : 0.f;
      ct32[n * 36 + up] = pk2(p0, p1);
    }
    // invQ: per-row inverse norms of Q (rows 0..195)
    if (tid < 208) {
      float s = 0.f;
      if (tid < 196) {
        const uint* qr = (const uint*)(Qg + gbase + (size_t)tid * HD);
#pragma unroll
        for (int g = 0; g < 48; ++g) {
          const uint pk = qr[g];
          const float a = u2f((ushort)(pk & 0xffff));
          const float b = u2f((ushort)(pk >> 16));
          s += a * a + b * b;
        }
      }
      invQ[tid] = 1.f / fmaxf(sqrtf(s), 1e-12f);
    }
  }
  __syncthreads();
  // ---- P0b: normalize K rows in LDS ----
  if (tid < 208) {
    uint* rowp = (uint*)(Klds + tid * KW);   // 48 u32 of data
    float s = 0.f;
#pragma unroll
    for (int g = 0; g < 48; ++g) {
      const uint pk = rowp[g];
      const float a = u2f((ushort)(pk & 0xffff));
      const float b = u2f((ushort)(pk >> 16));
      s += a * a + b * b;
    }
    const float inv = 1.f / fmaxf(sqrtf(s), 1e-12f);
#pragma unroll
    for (int g = 0; g < 48; ++g) {
      const uint pk = rowp[g];
      rowp[g] = pk2(u2f((ushort)(pk & 0xffff)) * inv, u2f((ushort)(pk >> 16)) * inv);
    }
  }
  __syncthreads();

  const int b_ = bt >> 6, head = (bt >> 3) & 7, tt = bt & 7;
  union PW { short8v v; uint u[4]; };
  const int rt = w;                       // one tile per wave
  f32x4 pacc[6];
#pragma unroll
  for (int ct = 0; ct < 6; ++ct) pacc[ct] = (f32x4){0.f, 0.f, 0.f, 0.f};

  // ---- P1: S^T -> scale by invQ -> corr extract -> softmax -> app PV ----
  if (rt < NT) {
    const int rq = (rt * 16 + lr > 195) ? 195 : rt * 16 + lr;
    short8v qf[3];
#pragma unroll
    for (int kc = 0; kc < 3; ++kc)
      qf[kc] = *(const short8v*)(Qg + gbase + (size_t)rq * HD + kc * 32 + lg * 8);
    f32x4 sacc[NT];
#pragma unroll
    for (int mt = 0; mt < NT; ++mt) sacc[mt] = (f32x4){0.f, 0.f, 0.f, 0.f};
    __builtin_amdgcn_s_setprio(1);
#pragma unroll
    for (int kc = 0; kc < 3; ++kc)
#pragma unroll
      for (int mt = 0; mt < NT; ++mt) {
        const short8v kf = *(const short8v*)&Klds[(mt * 16 + lr) * KW + kc * 32 + lg * 8];
        sacc[mt] = __builtin_amdgcn_mfma_f32_16x16x32_bf16(kf, qf[kc], sacc[mt], 0, 0, 0);
      }
    __builtin_amdgcn_s_setprio(0);
    // apply Q normalization (lane-constant: query = rq)
    const float iq = invQ[rq];
#pragma unroll
    for (int mt = 0; mt < NT; ++mt) {
      sacc[mt][0] *= iq; sacc[mt][1] *= iq; sacc[mt][2] *= iq; sacc[mt][3] *= iq;
    }
    // corr extraction (normalized S): query = rt*16+lr, keys = mt*16+lg*4+r
    const int rowg = rt * 16 + lr;
    if (rowg < 196) {
      const int h = rowg / 14, wq = rowg - (rowg / 14) * 14;
      int h2 = 0, w2 = lg * 4;
#pragma unroll
      for (int mt = 0; mt < NT; ++mt) {
        int hh = h2, ww = w2;
#pragma unroll
        for (int r = 0; r < 4; ++r) {
          if (mt < 12 || lg * 4 + r < 4) {
            const int dh = hh - h + 3, dw = ww - wq + 3;
            if (((unsigned)dh < 7u) && ((unsigned)dw < 7u)) {
              bf16* cp = &corrT[rowg * UW + dh * 7 + dw];
              *cp = f2b(b2f(*cp) + sacc[mt][r]);
            }
          }
          if (++ww == 14) { ww = 0; ++hh; }
        }
        w2 += 2; h2 += 1; if (w2 >= 14) { w2 -= 14; h2 += 1; }
      }
    }
    // softmax over keys (0.5 folded)
    float m0 = -1e30f, m1 = -1e30f, m2 = -1e30f, m3 = -1e30f;
#pragma unroll
    for (int mt = 0; mt < 12; ++mt) {
      m0 = fmaxf(m0, sacc[mt][0]); m1 = fmaxf(m1, sacc[mt][1]);
      m2 = fmaxf(m2, sacc[mt][2]); m3 = fmaxf(m3, sacc[mt][3]);
    }
    if (lg == 0) {
      m0 = fmaxf(m0, sacc[12][0]); m1 = fmaxf(m1, sacc[12][1]);
      m2 = fmaxf(m2, sacc[12][2]); m3 = fmaxf(m3, sacc[12][3]);
    }
    float mx = fmaxf(fmaxf(m0, m1), fmaxf(m2, m3));
    mx = fmaxf(mx, __shfl_xor(mx, 16));
    mx = fmaxf(mx, __shfl_xor(mx, 32));
    float s0 = 0.f, s1 = 0.f, s2 = 0.f, s3 = 0.f;
#pragma unroll
    for (int mt = 0; mt < NT; ++mt) {
      const bool dead = (mt == 12) && (lg != 0);
      const float e0 = dead ? 0.f : __expf(sacc[mt][0] - mx);
      const float e1 = dead ? 0.f : __expf(sacc[mt][1] - mx);
      const float e2 = dead ? 0.f : __expf(sacc[mt][2] - mx);
      const float e3 = dead ? 0.f : __expf(sacc[mt][3] - mx);
      sacc[mt][0] = e0; sacc[mt][1] = e1; sacc[mt][2] = e2; sacc[mt][3] = e3;
      s0 += e0; s1 += e1; s2 += e2; s3 += e3;
    }
    float s = (s0 + s1) + (s2 + s3);
    s += __shfl_xor(s, 16); s += __shfl_xor(s, 32);
    const float sc = 0.5f / s;
    PW pf[7];
#pragma unroll
    for (int kb = 0; kb < 7; ++kb) {
      pf[kb].u[0] = pk2(sacc[2 * kb][0] * sc, sacc[2 * kb][1] * sc);
      pf[kb].u[1] = pk2(sacc[2 * kb][2] * sc, sacc[2 * kb][3] * sc);
      if (kb < 6) {
        pf[kb].u[2] = pk2(sacc[2 * kb + 1][0] * sc, sacc[2 * kb + 1][1] * sc);
        pf[kb].u[3] = pk2(sacc[2 * kb + 1][2] * sc, sacc[2 * kb + 1][3] * sc);
      } else { pf[kb].u[2] = 0u; pf[kb].u[3] = 0u; }
    }
    __builtin_amdgcn_s_setprio(1);
#pragma unroll
    for (int ct = 0; ct < 6; ++ct) {
      const int c = ct * 16 + lr;
#pragma unroll
      for (int kb = 0; kb < 7; ++kb) {
        const uint2 lo = *(const uint2*)&Vt[c * VW2 + (2 * kb) * 16 + lg * 4];
        const uint2 hi = (kb < 6) ? *(const uint2*)&Vt[c * VW2 + (2 * kb + 1) * 16 + lg * 4] : lo;
        PW vf; vf.u[0] = lo.x; vf.u[1] = lo.y; vf.u[2] = hi.x; vf.u[3] = hi.y;
        pacc[ct] = __builtin_amdgcn_mfma_f32_16x16x32_bf16(pf[kb].v, vf.v, pacc[ct], 0, 0, 0);
      }
    }
    __builtin_amdgcn_s_setprio(0);
  }
  __syncthreads();

  // ---- P2: M = corrT.corrT^T -> softmax -> PV (+= into pacc) -> store ----
  if (rt < NT) {
    short8v cq[2];
#pragma unroll
    for (int kc = 0; kc < 2; ++kc)
      cq[kc] = *(const short8v*)&corrT[(rt * 16 + lr) * UW + kc * 32 + lg * 8];
    f32x4 macc[NT];
#pragma unroll
    for (int mt = 0; mt < NT; ++mt) macc[mt] = (f32x4){0.f, 0.f, 0.f, 0.f};
    __builtin_amdgcn_s_setprio(1);
#pragma unroll
    for (int kc = 0; kc < 2; ++kc)
#pragma unroll
      for (int mt = 0; mt < NT; ++mt) {
        const short8v ca = *(const short8v*)&corrT[(mt * 16 + lr) * UW + kc * 32 + lg * 8];
        macc[mt] = __builtin_amdgcn_mfma_f32_16x16x32_bf16(ca, cq[kc], macc[mt], 0, 0, 0);
      }
    __builtin_amdgcn_s_setprio(0);
    float m0 = -1e30f, m1 = -1e30f, m2 = -1e30f, m3 = -1e30f;
#pragma unroll
    for (int mt = 0; mt < 12; ++mt) {
      m0 = fmaxf(m0, macc[mt][0]); m1 = fmaxf(m1, macc[mt][1]);
      m2 = fmaxf(m2, macc[mt][2]); m3 = fmaxf(m3, macc[mt][3]);
    }
    if (lg == 0) {
      m0 = fmaxf(m0, macc[12][0]); m1 = fmaxf(m1, macc[12][1]);
      m2 = fmaxf(m2, macc[12][2]); m3 = fmaxf(m3, macc[12][3]);
    }
    float mx = fmaxf(fmaxf(m0, m1), fmaxf(m2, m3));
    mx = fmaxf(mx, __shfl_xor(mx, 16));
    mx = fmaxf(mx, __shfl_xor(mx, 32));
    float s0 = 0.f, s1 = 0.f, s2 = 0.f, s3 = 0.f;
#pragma unroll
    for (int mt = 0; mt < NT; ++mt) {
      const bool dead = (mt == 12) && (lg != 0);
      const float e0 = dead ? 0.f : __expf(macc[mt][0] - mx);
      const float e1 = dead ? 0.f : __expf(macc[mt][1] - mx);
      const float e2 = dead ? 0.f : __expf(macc[mt][2] - mx);
      const float e3 = dead ? 0.f : __expf(macc[mt][3] - mx);
      macc[mt][0] = e0; macc[mt][1] = e1; macc[mt][2] = e2; macc[mt][3] = e3;
      s0 += e0; s1 += e1; s2 += e2; s3 += e3;
    }
    float s = (s0 + s1) + (s2 + s3);
    s += __shfl_xor(s, 16); s += __shfl_xor(s, 32);
    const float sc = 0.5f / s;
    PW pf[7];
#pragma unroll
    for (int kb = 0; kb < 7; ++kb) {
      pf[kb].u[0] = pk2(macc[2 * kb][0] * sc, macc[2 * kb][1] * sc);
      pf[kb].u[1] = pk2(macc[2 * kb][2] * sc, macc[2 * kb][3] * sc);
      if (kb < 6) {
        pf[kb].u[2] = pk2(macc[2 * kb + 1][0] * sc, macc[2 * kb + 1][1] * sc);
        pf[kb].u[3] = pk2(macc[2 * kb + 1][2] * sc, macc[2 * kb + 1][3] * sc);
      } else { pf[kb].u[2] = 0u; pf[kb].u[3] = 0u; }
    }
    __builtin_amdgcn_s_setprio(1);
#pragma unroll
    for (int ct = 0; ct < 6; ++ct) {
      const int c = ct * 16 + lr;
#pragma unroll
      for (int kb = 0; kb < 7; ++kb) {
        const uint2 lo = *(const uint2*)&Vt[c * VW2 + (2 * kb) * 16 + lg * 4];
        const uint2 hi = (kb < 6) ? *(const uint2*)&Vt[c * VW2 + (2 * kb + 1) * 16 + lg * 4] : lo;
        PW vf; vf.u[0] = lo.x; vf.u[1] = lo.y; vf.u[2] = hi.x; vf.u[3] = hi.y;
        pacc[ct] = __builtin_amdgcn_mfma_f32_16x16x32_bf16(pf[kb].v, vf.v, pacc[ct], 0, 0, 0);
      }
    }
    __builtin_amdgcn_s_setprio(0);
    // single merged store: 0.5*(app+motion)
#pragma unroll
    for (int r = 0; r < 4; ++r) {
      const int rowq = rt * 16 + lg * 4 + r;
      if (rowq < 196) {
        const size_t ob = ((size_t)(b_ * NTOK + tt * HW + rowq)) * C + head * HD;
#pragma unroll
        for (int ct = 0; ct < 6; ++ct)
          merged[ob + ct * 16 + lr] = f2b(pacc[ct][r]);
      }
    }
  }
}

}  // namespace

extern "C" void kernel_launch(void* const* d_in, const int* in_sizes, int n_in,
                              void* d_out, int out_size, void* d_ws, size_t ws_size,
                              hipStream_t stream) {
  (void)in_sizes; (void)n_in; (void)out_size; (void)ws_size;
  const float* x      = (const float*)d_in[0];
  const float* w_qkv  = (const float*)d_in[1];
  const float* w_proj = (const float*)d_in[2];
  const float* b_proj = (const float*)d_in[3];
  const float* pos    = (const float*)d_in[4];
  float* out = (float*)d_out;

  char* p = (char*)d_ws;
  bf16* Qb = (bf16*)p;      p += (size_t)BHT * CHW * sizeof(bf16);    // 38.5 MB
  bf16* Kb = (bf16*)p;      p += (size_t)BHT * CHW * sizeof(bf16);    // 38.5 MB
  bf16* Vb = (bf16*)p;      p += (size_t)BHT * CHW * sizeof(bf16);    // 38.5 MB
  bf16* xbm = (bf16*)p;     p += (size_t)NROWS * C * sizeof(bf16);    // 38.5 MB (xb, then merged)
  bf16* wqkvT = (bf16*)p;   p += (size_t)C3 * C * sizeof(bf16);       // 3.5 MB
  bf16* wprojT = (bf16*)p;  p += (size_t)C * C * sizeof(bf16);        // 1.2 MB
  // total ws: ~159 MB

  conv_to_bf16<<<(NROWS * C / 8 + 255) / 256, 256, 0, stream>>>(x, xbm, NROWS * C / 8);
  transpose_to_bf16<<<dim3(C3 / 64, C / 64), 256, 0, stream>>>(w_qkv, wqkvT, C, C3);
  transpose_to_bf16<<<dim3(C / 64, C / 64), 256, 0, stream>>>(w_proj, wprojT, C, C);
  gemm_qkv_mfma<<<3528, 256, 0, stream>>>(xbm, wqkvT, Qb, Kb, Vb);
  fused_attn<<<BHT, 1024, 0, stream>>>(Qb, Kb, Vb, pos, xbm /*merged*/);
  gemm_proj_mfma<<<1176, 256, 0, stream>>>(xbm, wprojT, b_proj, out);
}

// Round 11
// 311.933 us; speedup vs baseline: 1.1185x; 1.1185x over previous
//
#include <hip/hip_runtime.h>
#include <hip/hip_bf16.h>

namespace {

constexpr int T = 8, HW = 196;
constexpr int C = 768, NH = 8, HD = 96;
constexpr int NTOK = 1568;
constexpr int BHT = 1024;          // B*NH*T
constexpr int C3 = 2304;           // 3*C
constexpr int CHW = HD * HW;       // 18816
constexpr int NROWS = 25088;       // B*NTOK
constexpr int NT = 13;             // 16-row tiles covering 208 >= 196
constexpr int KW = 104;            // Klds row stride (bf16)
constexpr int VW2 = 212;           // Vt row stride (bf16)
constexpr int UW = 72;             // corrT row stride
constexpr int TSZ = 128 * 64;      // one GEMM LDS tile (elems)

using bf16 = __hip_bfloat16;
typedef __attribute__((ext_vector_type(8))) short short8v;  // 8 x bf16 frag
typedef __attribute__((ext_vector_type(4))) float f32x4;

__device__ __forceinline__ float b2f(bf16 h) { return __bfloat162float(h); }
__device__ __forceinline__ bf16 f2b(float f) { return __float2bfloat16(f); }
__device__ __forceinline__ float u2f(ushort u) {
  union { ushort u[2]; float f; } x; x.u[0] = 0; x.u[1] = u; return x.f;
}
__device__ __forceinline__ ushort b2u(bf16 h) { union { bf16 b; ushort u; } x; x.b = h; return x.u; }
__device__ __forceinline__ uint pk2(float lo, float hi) {
  return ((uint)b2u(f2b(hi)) << 16) | (uint)b2u(f2b(lo));
}
__device__ __forceinline__ void gload_lds16(const bf16* g, bf16* l) {
  __builtin_amdgcn_global_load_lds(
      (const __attribute__((address_space(1))) unsigned int*)g,
      (__attribute__((address_space(3))) unsigned int*)l, 16, 0, 0);
}

// ---------------------------------------------------------------------------
// K0a: elementwise f32 -> bf16 (8 elems / thread)
// ---------------------------------------------------------------------------
__global__ __launch_bounds__(256) void conv_to_bf16(
    const float* __restrict__ X, bf16* __restrict__ Y, int n8) {
  const int i = blockIdx.x * 256 + threadIdx.x;
  if (i >= n8) return;
  const float4 a = ((const float4*)X)[i * 2];
  const float4 b = ((const float4*)X)[i * 2 + 1];
  uint4 o;
  o.x = pk2(a.x, a.y); o.y = pk2(a.z, a.w);
  o.z = pk2(b.x, b.y); o.w = pk2(b.z, b.w);
  ((uint4*)Y)[i] = o;
}

// ---------------------------------------------------------------------------
// K0b: W [rows][cols] f32 -> Wt [cols][rows] bf16, 64x64 LDS tiles.
// ---------------------------------------------------------------------------
__global__ __launch_bounds__(256) void transpose_to_bf16(
    const float* __restrict__ W, bf16* __restrict__ Wt, int rows, int cols) {
  __shared__ __align__(16) bf16 Lt[64][72];
  const int r0 = blockIdx.y * 64, c0 = blockIdx.x * 64;
  const int tid = threadIdx.x;
  const int r = tid >> 2, q = (tid & 3) * 16;
  const float* src = W + (size_t)(r0 + r) * cols + c0 + q;
#pragma unroll
  for (int i = 0; i < 16; i += 4) {
    const float4 v = *(const float4*)(src + i);
    Lt[q + i + 0][r] = f2b(v.x);
    Lt[q + i + 1][r] = f2b(v.y);
    Lt[q + i + 2][r] = f2b(v.z);
    Lt[q + i + 3][r] = f2b(v.w);
  }
  __syncthreads();
  const int c = tid >> 2, kc = (tid & 3) * 16;
  uint4* dst = (uint4*)(Wt + (size_t)(c0 + c) * rows + r0 + kc);
  const uint4* srcl = (const uint4*)(&Lt[c][kc]);
  dst[0] = srcl[0];
  dst[1] = srcl[1];
}

// ---------------------------------------------------------------------------
// Shared 128x128xK=768 MFMA core, double-buffered + T2 XOR-swizzled LDS.
// Swizzle involution on byte bits [6:4]: LDS slot (row, b) holds global
// (row, b ^ ((row&7)<<4)). Staging pre-swizzles the per-lane GLOBAL source
// (global_load_lds dest is linear lane*16 — rule #21); fragment reads apply
// the same XOR. Each bank gets exactly 8 touches per wave64 b128 read (floor).
// ---------------------------------------------------------------------------
__device__ __forceinline__ void gemm128_core(
    const bf16* __restrict__ A, const bf16* __restrict__ Bt,
    int rt, int ct, bf16* As, bf16* Bs, f32x4 acc[4][4]) {
  const int tid = threadIdx.x;
  const int w = tid >> 6, lane = tid & 63;
  const int lr = lane & 15, lg = lane >> 4;
  const int wr = w >> 1, wc = w & 1;
  const int crow = (lane >> 3);                       // row within 8-row chunk
  const int cole = ((lane & 7) ^ crow) << 3;          // pre-swizzled src elem
#pragma unroll
  for (int i = 0; i < 4; ++i)
#pragma unroll
    for (int j = 0; j < 4; ++j) acc[i][j] = (f32x4){0.f, 0.f, 0.f, 0.f};

#define STAGE_T(kt, dA, dB)                                                   \
  {                                                                           \
    const int k0s = (kt) * 64;                                                \
    _Pragma("unroll") for (int i = 0; i < 4; ++i) {                           \
      const int chunk = w * 4 + i;                                            \
      const int row = chunk * 8 + crow;                                       \
      gload_lds16(A + (size_t)(rt + row) * 768 + k0s + cole, (dA) + chunk * 512); \
      gload_lds16(Bt + (size_t)(ct + row) * 768 + k0s + cole, (dB) + chunk * 512); \
    }                                                                         \
  }

  STAGE_T(0, As, Bs);
  __syncthreads();
#pragma unroll
  for (int kt = 0; kt < 12; ++kt) {
    const int cur = (kt & 1) * TSZ;
    const int nxt = ((kt + 1) & 1) * TSZ;
    if (kt + 1 < 12) STAGE_T(kt + 1, As + nxt, Bs + nxt);
#pragma unroll
    for (int kc = 0; kc < 2; ++kc) {
      const int roff = ((kc * 4 + lg) ^ (lr & 7)) << 3;  // swizzled read elem
      short8v xa[4], wb[4];
#pragma unroll
      for (int f = 0; f < 4; ++f) {
        xa[f] = *(const short8v*)(As + cur + (wr * 64 + f * 16 + lr) * 64 + roff);
        wb[f] = *(const short8v*)(Bs + cur + (wc * 64 + f * 16 + lr) * 64 + roff);
      }
#pragma unroll
      for (int cj = 0; cj < 4; ++cj)
#pragma unroll
        for (int ri = 0; ri < 4; ++ri)
          acc[cj][ri] = __builtin_amdgcn_mfma_f32_16x16x32_bf16(wb[cj], xa[ri], acc[cj][ri], 0, 0, 0);
    }
    __syncthreads();   // drains vmcnt(0): next tile landed; lgkm: reads done
  }
#undef STAGE_T
}

// ---------------------------------------------------------------------------
// K1: QKV GEMM, scatter epilogue to Q / K(shifted) / V (all unnormalized).
// ---------------------------------------------------------------------------
__global__ __launch_bounds__(256) void gemm_qkv_mfma(
    const bf16* __restrict__ A, const bf16* __restrict__ Bt,
    bf16* __restrict__ Qo, bf16* __restrict__ Ko, bf16* __restrict__ Vo) {
  __shared__ __align__(16) bf16 As[2 * TSZ];
  __shared__ __align__(16) bf16 Bs[2 * TSZ];
  const int id = blockIdx.x;
  const int sw = (id & 7) * 441 + (id >> 3);   // 3528 = 8 * 441 (bijective)
  const int cti = sw % 18, rti = sw / 18;
  const int ct = cti * 128, rt = rti * 128;
  const int tid = threadIdx.x;
  const int w = tid >> 6, lane = tid & 63;
  const int lr = lane & 15, lg = lane >> 4;
  const int wr = w >> 1, wc = w & 1;

  f32x4 acc[4][4];
  gemm128_core(A, Bt, rt, ct, As, Bs, acc);

  const int s = cti / 6;
#pragma unroll
  for (int ri = 0; ri < 4; ++ri) {
    const int row = rt + wr * 64 + ri * 16 + lr;
    const int b_ = row / NTOK, n = row % NTOK;
    const int t = n / HW, hw = n % HW;
#pragma unroll
    for (int cj = 0; cj < 4; ++cj) {
      const int colb = ct + wc * 64 + cj * 16 + lg * 4;
      const int rem = colb - s * C;
      const int head = rem / HD, chb = rem - head * HD;
      const int bh = b_ * NH + head;
      if (s == 0) {
        uint2 pk;
        pk.x = pk2(acc[cj][ri][0], acc[cj][ri][1]);
        pk.y = pk2(acc[cj][ri][2], acc[cj][ri][3]);
        *(uint2*)(Qo + (size_t)(bh * T + t) * CHW + hw * HD + chb) = pk;
      } else if (s == 1) {
        uint2 pk;
        pk.x = pk2(acc[cj][ri][0], acc[cj][ri][1]);
        pk.y = pk2(acc[cj][ri][2], acc[cj][ri][3]);
        if (t >= 1)
          *(uint2*)(Ko + (size_t)(bh * T + t - 1) * CHW + hw * HD + chb) = pk;
        if (t == T - 1)
          *(uint2*)(Ko + (size_t)(bh * T + t) * CHW + hw * HD + chb) = pk;
      } else {
#pragma unroll
        for (int j = 0; j < 4; ++j)
          Vo[(size_t)(bh * T + t) * CHW + (chb + j) * HW + hw] = f2b(acc[cj][ri][j]);
      }
    }
  }
}

// ---------------------------------------------------------------------------
// K4: proj GEMM + bias -> out f32.
// ---------------------------------------------------------------------------
__global__ __launch_bounds__(256) void gemm_proj_mfma(
    const bf16* __restrict__ A, const bf16* __restrict__ Bt,
    const float* __restrict__ bias, float* __restrict__ out) {
  __shared__ __align__(16) bf16 As[2 * TSZ];
  __shared__ __align__(16) bf16 Bs[2 * TSZ];
  const int id = blockIdx.x;
  const int sw = (id & 7) * 147 + (id >> 3);   // 1176 = 8 * 147 (bijective)
  const int cti = sw % 6, rti = sw / 6;
  const int ct = cti * 128, rt = rti * 128;
  const int tid = threadIdx.x;
  const int w = tid >> 6, lane = tid & 63;
  const int lr = lane & 15, lg = lane >> 4;
  const int wr = w >> 1, wc = w & 1;

  f32x4 acc[4][4];
  gemm128_core(A, Bt, rt, ct, As, Bs, acc);

#pragma unroll
  for (int ri = 0; ri < 4; ++ri) {
    const int row = rt + wr * 64 + ri * 16 + lr;
#pragma unroll
    for (int cj = 0; cj < 4; ++cj) {
      const int colb = ct + wc * 64 + cj * 16 + lg * 4;
      const float4 bv = *(const float4*)(bias + colb);
      float4 o;
      o.x = acc[cj][ri][0] + bv.x;
      o.y = acc[cj][ri][1] + bv.y;
      o.z = acc[cj][ri][2] + bv.z;
      o.w = acc[cj][ri][3] + bv.w;
      *(float4*)(out + (size_t)row * C + colb) = o;
    }
  }
}

// ---------------------------------------------------------------------------
// K3: fused l2norm + corr + appearance + motion attention per bt.
// 1024 threads, 16 waves, one 16-row tile per wave (4 waves/SIMD).
// ---------------------------------------------------------------------------
__global__ __launch_bounds__(1024, 1) void fused_attn(
    const bf16* __restrict__ Qg, const bf16* __restrict__ Kg,
    const bf16* __restrict__ Vg, const float* __restrict__ pos,
    bf16* __restrict__ merged) {
  __shared__ __align__(16) bf16 Klds[208 * KW];    // 43,264 B  K tokens x ch
  __shared__ __align__(16) bf16 Vt[96 * VW2];      // 40,704 B  V^T: ch x tok
  __shared__ __align__(16) bf16 corrT[208 * UW];   // 29,952 B  tok x disp(64pad)
  __shared__ float invQ[208];                      //     832 B
  const int bt = blockIdx.x;
  const int tid = threadIdx.x;
  const int w = tid >> 6, lane = tid & 63;
  const int lr = lane & 15, lg = lane >> 4;
  const size_t gbase = (size_t)bt * CHW;

  // ---- P0: staging + invQ ----
  {
    const uint4* kg = (const uint4*)(Kg + gbase);             // 196 rows x 12
    uint4* kl = (uint4*)Klds;                                 // 13 uint4/row
    for (int i = tid; i < 196 * 12; i += 1024) { const int r = i / 12, g = i - r * 12; kl[r * 13 + g] = kg[i]; }
    const uint4 z4 = make_uint4(0u, 0u, 0u, 0u);
    for (int i = tid; i < 12 * 13; i += 1024) { const int r = 196 + i / 13, g = i % 13; kl[r * 13 + g] = z4; }
    const uint* vg = (const uint*)(Vg + gbase);               // 96 x 98 u32
    uint* vl = (uint*)Vt;                                     // 106 u32/row
    for (int i = tid; i < 96 * 98; i += 1024) { const int c = i / 98, g = i - c * 98; vl[c * 106 + g] = vg[i]; }
    for (int i = tid; i < 96 * 8; i += 1024)  { const int c = i / 8, g = 98 + (i & 7); vl[c * 106 + g] = 0u; }
    uint* ct32 = (uint*)corrT;                                // 36 u32/row
    for (int i = tid; i < 208 * 36; i += 1024) {
      const int n = i % 208, up = i / 208;
      const int u0 = 2 * up, u1 = u0 + 1;
      const float p0 = (n < 196 && u0 < 49) ? pos[u0 * 196 + n] : 0.f;
      const float p1 = (n < 196 && u1 < 49) ? pos[u1 * 196 + n] : 0.f;
      ct32[n * 36 + up] = pk2(p0, p1);
    }
    // invQ: per-row inverse norms of Q (rows 0..195)
    if (tid < 208) {
      float s = 0.f;
      if (tid < 196) {
        const uint* qr = (const uint*)(Qg + gbase + (size_t)tid * HD);
#pragma unroll
        for (int g = 0; g < 48; ++g) {
          const uint pk = qr[g];
          const float a = u2f((ushort)(pk & 0xffff));
          const float b = u2f((ushort)(pk >> 16));
          s += a * a + b * b;
        }
      }
      invQ[tid] = 1.f / fmaxf(sqrtf(s), 1e-12f);
    }
  }
  __syncthreads();
  // ---- P0b: normalize K rows in LDS ----
  if (tid < 208) {
    uint* rowp = (uint*)(Klds + tid * KW);   // 48 u32 of data
    float s = 0.f;
#pragma unroll
    for (int g = 0; g < 48; ++g) {
      const uint pk = rowp[g];
      const float a = u2f((ushort)(pk & 0xffff));
      const float b = u2f((ushort)(pk >> 16));
      s += a * a + b * b;
    }
    const float inv = 1.f / fmaxf(sqrtf(s), 1e-12f);
#pragma unroll
    for (int g = 0; g < 48; ++g) {
      const uint pk = rowp[g];
      rowp[g] = pk2(u2f((ushort)(pk & 0xffff)) * inv, u2f((ushort)(pk >> 16)) * inv);
    }
  }
  __syncthreads();

  const int b_ = bt >> 6, head = (bt >> 3) & 7, tt = bt & 7;
  union PW { short8v v; uint u[4]; };
  const int rt = w;                       // one tile per wave
  f32x4 pacc[6];
#pragma unroll
  for (int ct = 0; ct < 6; ++ct) pacc[ct] = (f32x4){0.f, 0.f, 0.f, 0.f};

  // ---- P1: S^T -> scale by invQ -> corr extract -> softmax -> app PV ----
  if (rt < NT) {
    const int rq = (rt * 16 + lr > 195) ? 195 : rt * 16 + lr;
    short8v qf[3];
#pragma unroll
    for (int kc = 0; kc < 3; ++kc)
      qf[kc] = *(const short8v*)(Qg + gbase + (size_t)rq * HD + kc * 32 + lg * 8);
    f32x4 sacc[NT];
#pragma unroll
    for (int mt = 0; mt < NT; ++mt) sacc[mt] = (f32x4){0.f, 0.f, 0.f, 0.f};
    __builtin_amdgcn_s_setprio(1);
#pragma unroll
    for (int kc = 0; kc < 3; ++kc)
#pragma unroll
      for (int mt = 0; mt < NT; ++mt) {
        const short8v kf = *(const short8v*)&Klds[(mt * 16 + lr) * KW + kc * 32 + lg * 8];
        sacc[mt] = __builtin_amdgcn_mfma_f32_16x16x32_bf16(kf, qf[kc], sacc[mt], 0, 0, 0);
      }
    __builtin_amdgcn_s_setprio(0);
    // apply Q normalization (lane-constant: query = rq)
    const float iq = invQ[rq];
#pragma unroll
    for (int mt = 0; mt < NT; ++mt) {
      sacc[mt][0] *= iq; sacc[mt][1] *= iq; sacc[mt][2] *= iq; sacc[mt][3] *= iq;
    }
    // corr extraction (normalized S): query = rt*16+lr, keys = mt*16+lg*4+r
    const int rowg = rt * 16 + lr;
    if (rowg < 196) {
      const int h = rowg / 14, wq = rowg - (rowg / 14) * 14;
      int h2 = 0, w2 = lg * 4;
#pragma unroll
      for (int mt = 0; mt < NT; ++mt) {
        int hh = h2, ww = w2;
#pragma unroll
        for (int r = 0; r < 4; ++r) {
          if (mt < 12 || lg * 4 + r < 4) {
            const int dh = hh - h + 3, dw = ww - wq + 3;
            if (((unsigned)dh < 7u) && ((unsigned)dw < 7u)) {
              bf16* cp = &corrT[rowg * UW + dh * 7 + dw];
              *cp = f2b(b2f(*cp) + sacc[mt][r]);
            }
          }
          if (++ww == 14) { ww = 0; ++hh; }
        }
        w2 += 2; h2 += 1; if (w2 >= 14) { w2 -= 14; h2 += 1; }
      }
    }
    // softmax over keys (0.5 folded)
    float m0 = -1e30f, m1 = -1e30f, m2 = -1e30f, m3 = -1e30f;
#pragma unroll
    for (int mt = 0; mt < 12; ++mt) {
      m0 = fmaxf(m0, sacc[mt][0]); m1 = fmaxf(m1, sacc[mt][1]);
      m2 = fmaxf(m2, sacc[mt][2]); m3 = fmaxf(m3, sacc[mt][3]);
    }
    if (lg == 0) {
      m0 = fmaxf(m0, sacc[12][0]); m1 = fmaxf(m1, sacc[12][1]);
      m2 = fmaxf(m2, sacc[12][2]); m3 = fmaxf(m3, sacc[12][3]);
    }
    float mx = fmaxf(fmaxf(m0, m1), fmaxf(m2, m3));
    mx = fmaxf(mx, __shfl_xor(mx, 16));
    mx = fmaxf(mx, __shfl_xor(mx, 32));
    float s0 = 0.f, s1 = 0.f, s2 = 0.f, s3 = 0.f;
#pragma unroll
    for (int mt = 0; mt < NT; ++mt) {
      const bool dead = (mt == 12) && (lg != 0);
      const float e0 = dead ? 0.f : __expf(sacc[mt][0] - mx);
      const float e1 = dead ? 0.f : __expf(sacc[mt][1] - mx);
      const float e2 = dead ? 0.f : __expf(sacc[mt][2] - mx);
      const float e3 = dead ? 0.f : __expf(sacc[mt][3] - mx);
      sacc[mt][0] = e0; sacc[mt][1] = e1; sacc[mt][2] = e2; sacc[mt][3] = e3;
      s0 += e0; s1 += e1; s2 += e2; s3 += e3;
    }
    float s = (s0 + s1) + (s2 + s3);
    s += __shfl_xor(s, 16); s += __shfl_xor(s, 32);
    const float sc = 0.5f / s;
    PW pf[7];
#pragma unroll
    for (int kb = 0; kb < 7; ++kb) {
      pf[kb].u[0] = pk2(sacc[2 * kb][0] * sc, sacc[2 * kb][1] * sc);
      pf[kb].u[1] = pk2(sacc[2 * kb][2] * sc, sacc[2 * kb][3] * sc);
      if (kb < 6) {
        pf[kb].u[2] = pk2(sacc[2 * kb + 1][0] * sc, sacc[2 * kb + 1][1] * sc);
        pf[kb].u[3] = pk2(sacc[2 * kb + 1][2] * sc, sacc[2 * kb + 1][3] * sc);
      } else { pf[kb].u[2] = 0u; pf[kb].u[3] = 0u; }
    }
    __builtin_amdgcn_s_setprio(1);
#pragma unroll
    for (int ct = 0; ct < 6; ++ct) {
      const int c = ct * 16 + lr;
#pragma unroll
      for (int kb = 0; kb < 7; ++kb) {
        const uint2 lo = *(const uint2*)&Vt[c * VW2 + (2 * kb) * 16 + lg * 4];
        const uint2 hi = (kb < 6) ? *(const uint2*)&Vt[c * VW2 + (2 * kb + 1) * 16 + lg * 4] : lo;
        PW vf; vf.u[0] = lo.x; vf.u[1] = lo.y; vf.u[2] = hi.x; vf.u[3] = hi.y;
        pacc[ct] = __builtin_amdgcn_mfma_f32_16x16x32_bf16(pf[kb].v, vf.v, pacc[ct], 0, 0, 0);
      }
    }
    __builtin_amdgcn_s_setprio(0);
  }
  __syncthreads();

  // ---- P2: M = corrT.corrT^T -> softmax -> PV (+= into pacc) -> store ----
  if (rt < NT) {
    short8v cq[2];
#pragma unroll
    for (int kc = 0; kc < 2; ++kc)
      cq[kc] = *(const short8v*)&corrT[(rt * 16 + lr) * UW + kc * 32 + lg * 8];
    f32x4 macc[NT];
#pragma unroll
    for (int mt = 0; mt < NT; ++mt) macc[mt] = (f32x4){0.f, 0.f, 0.f, 0.f};
    __builtin_amdgcn_s_setprio(1);
#pragma unroll
    for (int kc = 0; kc < 2; ++kc)
#pragma unroll
      for (int mt = 0; mt < NT; ++mt) {
        const short8v ca = *(const short8v*)&corrT[(mt * 16 + lr) * UW + kc * 32 + lg * 8];
        macc[mt] = __builtin_amdgcn_mfma_f32_16x16x32_bf16(ca, cq[kc], macc[mt], 0, 0, 0);
      }
    __builtin_amdgcn_s_setprio(0);
    float m0 = -1e30f, m1 = -1e30f, m2 = -1e30f, m3 = -1e30f;
#pragma unroll
    for (int mt = 0; mt < 12; ++mt) {
      m0 = fmaxf(m0, macc[mt][0]); m1 = fmaxf(m1, macc[mt][1]);
      m2 = fmaxf(m2, macc[mt][2]); m3 = fmaxf(m3, macc[mt][3]);
    }
    if (lg == 0) {
      m0 = fmaxf(m0, macc[12][0]); m1 = fmaxf(m1, macc[12][1]);
      m2 = fmaxf(m2, macc[12][2]); m3 = fmaxf(m3, macc[12][3]);
    }
    float mx = fmaxf(fmaxf(m0, m1), fmaxf(m2, m3));
    mx = fmaxf(mx, __shfl_xor(mx, 16));
    mx = fmaxf(mx, __shfl_xor(mx, 32));
    float s0 = 0.f, s1 = 0.f, s2 = 0.f, s3 = 0.f;
#pragma unroll
    for (int mt = 0; mt < NT; ++mt) {
      const bool dead = (mt == 12) && (lg != 0);
      const float e0 = dead ? 0.f : __expf(macc[mt][0] - mx);
      const float e1 = dead ? 0.f : __expf(macc[mt][1] - mx);
      const float e2 = dead ? 0.f : __expf(macc[mt][2] - mx);
      const float e3 = dead ? 0.f : __expf(macc[mt][3] - mx);
      macc[mt][0] = e0; macc[mt][1] = e1; macc[mt][2] = e2; macc[mt][3] = e3;
      s0 += e0; s1 += e1; s2 += e2; s3 += e3;
    }
    float s = (s0 + s1) + (s2 + s3);
    s += __shfl_xor(s, 16); s += __shfl_xor(s, 32);
    const float sc = 0.5f / s;
    PW pf[7];
#pragma unroll
    for (int kb = 0; kb < 7; ++kb) {
      pf[kb].u[0] = pk2(macc[2 * kb][0] * sc, macc[2 * kb][1] * sc);
      pf[kb].u[1] = pk2(macc[2 * kb][2] * sc, macc[2 * kb][3] * sc);
      if (kb < 6) {
        pf[kb].u[2] = pk2(macc[2 * kb + 1][0] * sc, macc[2 * kb + 1][1] * sc);
        pf[kb].u[3] = pk2(macc[2 * kb + 1][2] * sc, macc[2 * kb + 1][3] * sc);
      } else { pf[kb].u[2] = 0u; pf[kb].u[3] = 0u; }
    }
    __builtin_amdgcn_s_setprio(1);
#pragma unroll
    for (int ct = 0; ct < 6; ++ct) {
      const int c = ct * 16 + lr;
#pragma unroll
      for (int kb = 0; kb < 7; ++kb) {
        const uint2 lo = *(const uint2*)&Vt[c * VW2 + (2 * kb) * 16 + lg * 4];
        const uint2 hi = (kb < 6) ? *(const uint2*)&Vt[c * VW2 + (2 * kb + 1) * 16 + lg * 4] : lo;
        PW vf; vf.u[0] = lo.x; vf.u[1] = lo.y; vf.u[2] = hi.x; vf.u[3] = hi.y;
        pacc[ct] = __builtin_amdgcn_mfma_f32_16x16x32_bf16(pf[kb].v, vf.v, pacc[ct], 0, 0, 0);
      }
    }
    __builtin_amdgcn_s_setprio(0);
    // single merged store: 0.5*(app+motion)
#pragma unroll
    for (int r = 0; r < 4; ++r) {
      const int rowq = rt * 16 + lg * 4 + r;
      if (rowq < 196) {
        const size_t ob = ((size_t)(b_ * NTOK + tt * HW + rowq)) * C + head * HD;
#pragma unroll
        for (int ct = 0; ct < 6; ++ct)
          merged[ob + ct * 16 + lr] = f2b(pacc[ct][r]);
      }
    }
  }
}

}  // namespace

extern "C" void kernel_launch(void* const* d_in, const int* in_sizes, int n_in,
                              void* d_out, int out_size, void* d_ws, size_t ws_size,
                              hipStream_t stream) {
  (void)in_sizes; (void)n_in; (void)out_size; (void)ws_size;
  const float* x      = (const float*)d_in[0];
  const float* w_qkv  = (const float*)d_in[1];
  const float* w_proj = (const float*)d_in[2];
  const float* b_proj = (const float*)d_in[3];
  const float* pos    = (const float*)d_in[4];
  float* out = (float*)d_out;

  char* p = (char*)d_ws;
  bf16* Qb = (bf16*)p;      p += (size_t)BHT * CHW * sizeof(bf16);    // 38.5 MB
  bf16* Kb = (bf16*)p;      p += (size_t)BHT * CHW * sizeof(bf16);    // 38.5 MB
  bf16* Vb = (bf16*)p;      p += (size_t)BHT * CHW * sizeof(bf16);    // 38.5 MB
  bf16* xbm = (bf16*)p;     p += (size_t)NROWS * C * sizeof(bf16);    // 38.5 MB (xb, then merged)
  bf16* wqkvT = (bf16*)p;   p += (size_t)C3 * C * sizeof(bf16);       // 3.5 MB
  bf16* wprojT = (bf16*)p;  p += (size_t)C * C * sizeof(bf16);        // 1.2 MB
  // total ws: ~159 MB

  conv_to_bf16<<<(NROWS * C / 8 + 255) / 256, 256, 0, stream>>>(x, xbm, NROWS * C / 8);
  transpose_to_bf16<<<dim3(C3 / 64, C / 64), 256, 0, stream>>>(w_qkv, wqkvT, C, C3);
  transpose_to_bf16<<<dim3(C / 64, C / 64), 256, 0, stream>>>(w_proj, wprojT, C, C);
  gemm_qkv_mfma<<<3528, 256, 0, stream>>>(xbm, wqkvT, Qb, Kb, Vb);
  fused_attn<<<BHT, 1024, 0, stream>>>(Qb, Kb, Vb, pos, xbm /*merged*/);
  gemm_proj_mfma<<<1176, 256, 0, stream>>>(xbm, wprojT, b_proj, out);
}

// Round 12
// 295.851 us; speedup vs baseline: 1.1793x; 1.0544x over previous
//
#include <hip/hip_runtime.h>
#include <hip/hip_bf16.h>

namespace {

constexpr int T = 8, HW = 196;
constexpr int C = 768, NH = 8, HD = 96;
constexpr int NTOK = 1568;
constexpr int BHT = 1024;          // B*NH*T
constexpr int C3 = 2304;           // 3*C
constexpr int CHW = HD * HW;       // 18816
constexpr int NROWS = 25088;       // B*NTOK
constexpr int NT = 13;             // 16-row tiles covering 208 >= 196
constexpr int KW = 104;            // Klds row stride (bf16)
constexpr int VW2 = 212;           // Vt row stride (bf16)
constexpr int UW = 72;             // corrT row stride
constexpr int TSZ = 128 * 64;      // one GEMM LDS tile (elems)

using bf16 = __hip_bfloat16;
typedef __attribute__((ext_vector_type(8))) short short8v;  // 8 x bf16 frag
typedef __attribute__((ext_vector_type(4))) float f32x4;

__device__ __forceinline__ float b2f(bf16 h) { return __bfloat162float(h); }
__device__ __forceinline__ bf16 f2b(float f) { return __float2bfloat16(f); }
__device__ __forceinline__ float u2f(ushort u) {
  union { ushort u[2]; float f; } x; x.u[0] = 0; x.u[1] = u; return x.f;
}
__device__ __forceinline__ ushort b2u(bf16 h) { union { bf16 b; ushort u; } x; x.b = h; return x.u; }
__device__ __forceinline__ uint pk2(float lo, float hi) {
  return ((uint)b2u(f2b(hi)) << 16) | (uint)b2u(f2b(lo));
}
__device__ __forceinline__ void gload_lds16(const bf16* g, bf16* l) {
  __builtin_amdgcn_global_load_lds(
      (const __attribute__((address_space(1))) unsigned int*)g,
      (__attribute__((address_space(3))) unsigned int*)l, 16, 0, 0);
}

// ---------------------------------------------------------------------------
// K0a: elementwise f32 -> bf16 (8 elems / thread)
// ---------------------------------------------------------------------------
__global__ __launch_bounds__(256) void conv_to_bf16(
    const float* __restrict__ X, bf16* __restrict__ Y, int n8) {
  const int i = blockIdx.x * 256 + threadIdx.x;
  if (i >= n8) return;
  const float4 a = ((const float4*)X)[i * 2];
  const float4 b = ((const float4*)X)[i * 2 + 1];
  uint4 o;
  o.x = pk2(a.x, a.y); o.y = pk2(a.z, a.w);
  o.z = pk2(b.x, b.y); o.w = pk2(b.z, b.w);
  ((uint4*)Y)[i] = o;
}

// ---------------------------------------------------------------------------
// K0b: W [rows][cols] f32 -> Wt [cols][rows] bf16, 64x64 LDS tiles.
// ---------------------------------------------------------------------------
__global__ __launch_bounds__(256) void transpose_to_bf16(
    const float* __restrict__ W, bf16* __restrict__ Wt, int rows, int cols) {
  __shared__ __align__(16) bf16 Lt[64][72];
  const int r0 = blockIdx.y * 64, c0 = blockIdx.x * 64;
  const int tid = threadIdx.x;
  const int r = tid >> 2, q = (tid & 3) * 16;
  const float* src = W + (size_t)(r0 + r) * cols + c0 + q;
#pragma unroll
  for (int i = 0; i < 16; i += 4) {
    const float4 v = *(const float4*)(src + i);
    Lt[q + i + 0][r] = f2b(v.x);
    Lt[q + i + 1][r] = f2b(v.y);
    Lt[q + i + 2][r] = f2b(v.z);
    Lt[q + i + 3][r] = f2b(v.w);
  }
  __syncthreads();
  const int c = tid >> 2, kc = (tid & 3) * 16;
  uint4* dst = (uint4*)(Wt + (size_t)(c0 + c) * rows + r0 + kc);
  const uint4* srcl = (const uint4*)(&Lt[c][kc]);
  dst[0] = srcl[0];
  dst[1] = srcl[1];
}

// ---------------------------------------------------------------------------
// Shared 128x128xK=768 MFMA core, single-buffered (32 KB) + T2 XOR swizzle.
// Register budget: 88 arch VGPR + 64 acc = 152 < 170 -> 3 waves/SIMD;
// LDS 32 KB -> not binding (5 blocks). __launch_bounds__(256,3) pins it.
// Swizzle involution on byte bits [6:4] (proven in R11, conflicts = 0).
// ---------------------------------------------------------------------------
__device__ __forceinline__ void gemm128_core(
    const bf16* __restrict__ A, const bf16* __restrict__ Bt,
    int rt, int ct, bf16* As, bf16* Bs, f32x4 acc[4][4]) {
  const int tid = threadIdx.x;
  const int w = tid >> 6, lane = tid & 63;
  const int lr = lane & 15, lg = lane >> 4;
  const int wr = w >> 1, wc = w & 1;
  const int crow = (lane >> 3);                       // row within 8-row chunk
  const int cole = ((lane & 7) ^ crow) << 3;          // pre-swizzled src elem
#pragma unroll
  for (int i = 0; i < 4; ++i)
#pragma unroll
    for (int j = 0; j < 4; ++j) acc[i][j] = (f32x4){0.f, 0.f, 0.f, 0.f};

  for (int kt = 0; kt < 12; ++kt) {
    const int k0 = kt * 64;
    __syncthreads();
#pragma unroll
    for (int i = 0; i < 4; ++i) {
      const int chunk = w * 4 + i;                    // 16 chunks of 8 rows
      const int row = chunk * 8 + crow;
      gload_lds16(A + (size_t)(rt + row) * 768 + k0 + cole, As + chunk * 512);
      gload_lds16(Bt + (size_t)(ct + row) * 768 + k0 + cole, Bs + chunk * 512);
    }
    __syncthreads();
#pragma unroll
    for (int kc = 0; kc < 2; ++kc) {
      const int roff = ((kc * 4 + lg) ^ (lr & 7)) << 3;  // swizzled read elem
      short8v xa[4], wb[4];
#pragma unroll
      for (int f = 0; f < 4; ++f) {
        xa[f] = *(const short8v*)(As + (wr * 64 + f * 16 + lr) * 64 + roff);
        wb[f] = *(const short8v*)(Bs + (wc * 64 + f * 16 + lr) * 64 + roff);
      }
#pragma unroll
      for (int cj = 0; cj < 4; ++cj)
#pragma unroll
        for (int ri = 0; ri < 4; ++ri)
          acc[cj][ri] = __builtin_amdgcn_mfma_f32_16x16x32_bf16(wb[cj], xa[ri], acc[cj][ri], 0, 0, 0);
    }
  }
}

// ---------------------------------------------------------------------------
// K1: QKV GEMM, scatter epilogue to Q / K(shifted) / V (all unnormalized).
// ---------------------------------------------------------------------------
__global__ __launch_bounds__(256, 3) void gemm_qkv_mfma(
    const bf16* __restrict__ A, const bf16* __restrict__ Bt,
    bf16* __restrict__ Qo, bf16* __restrict__ Ko, bf16* __restrict__ Vo) {
  __shared__ __align__(16) bf16 As[TSZ];
  __shared__ __align__(16) bf16 Bs[TSZ];
  const int id = blockIdx.x;
  const int sw = (id & 7) * 441 + (id >> 3);   // 3528 = 8 * 441 (bijective)
  const int cti = sw % 18, rti = sw / 18;
  const int ct = cti * 128, rt = rti * 128;
  const int tid = threadIdx.x;
  const int w = tid >> 6, lane = tid & 63;
  const int lr = lane & 15, lg = lane >> 4;
  const int wr = w >> 1, wc = w & 1;

  f32x4 acc[4][4];
  gemm128_core(A, Bt, rt, ct, As, Bs, acc);

  const int s = cti / 6;
#pragma unroll
  for (int ri = 0; ri < 4; ++ri) {
    const int row = rt + wr * 64 + ri * 16 + lr;
    const int b_ = row / NTOK, n = row % NTOK;
    const int t = n / HW, hw = n % HW;
#pragma unroll
    for (int cj = 0; cj < 4; ++cj) {
      const int colb = ct + wc * 64 + cj * 16 + lg * 4;
      const int rem = colb - s * C;
      const int head = rem / HD, chb = rem - head * HD;
      const int bh = b_ * NH + head;
      if (s == 0) {
        uint2 pk;
        pk.x = pk2(acc[cj][ri][0], acc[cj][ri][1]);
        pk.y = pk2(acc[cj][ri][2], acc[cj][ri][3]);
        *(uint2*)(Qo + (size_t)(bh * T + t) * CHW + hw * HD + chb) = pk;
      } else if (s == 1) {
        uint2 pk;
        pk.x = pk2(acc[cj][ri][0], acc[cj][ri][1]);
        pk.y = pk2(acc[cj][ri][2], acc[cj][ri][3]);
        if (t >= 1)
          *(uint2*)(Ko + (size_t)(bh * T + t - 1) * CHW + hw * HD + chb) = pk;
        if (t == T - 1)
          *(uint2*)(Ko + (size_t)(bh * T + t) * CHW + hw * HD + chb) = pk;
      } else {
#pragma unroll
        for (int j = 0; j < 4; ++j)
          Vo[(size_t)(bh * T + t) * CHW + (chb + j) * HW + hw] = f2b(acc[cj][ri][j]);
      }
    }
  }
}

// ---------------------------------------------------------------------------
// K4: proj GEMM + bias -> out f32.
// ---------------------------------------------------------------------------
__global__ __launch_bounds__(256, 3) void gemm_proj_mfma(
    const bf16* __restrict__ A, const bf16* __restrict__ Bt,
    const float* __restrict__ bias, float* __restrict__ out) {
  __shared__ __align__(16) bf16 As[TSZ];
  __shared__ __align__(16) bf16 Bs[TSZ];
  const int id = blockIdx.x;
  const int sw = (id & 7) * 147 + (id >> 3);   // 1176 = 8 * 147 (bijective)
  const int cti = sw % 6, rti = sw / 6;
  const int ct = cti * 128, rt = rti * 128;
  const int tid = threadIdx.x;
  const int w = tid >> 6, lane = tid & 63;
  const int lr = lane & 15, lg = lane >> 4;
  const int wr = w >> 1, wc = w & 1;

  f32x4 acc[4][4];
  gemm128_core(A, Bt, rt, ct, As, Bs, acc);

#pragma unroll
  for (int ri = 0; ri < 4; ++ri) {
    const int row = rt + wr * 64 + ri * 16 + lr;
#pragma unroll
    for (int cj = 0; cj < 4; ++cj) {
      const int colb = ct + wc * 64 + cj * 16 + lg * 4;
      const float4 bv = *(const float4*)(bias + colb);
      float4 o;
      o.x = acc[cj][ri][0] + bv.x;
      o.y = acc[cj][ri][1] + bv.y;
      o.z = acc[cj][ri][2] + bv.z;
      o.w = acc[cj][ri][3] + bv.w;
      *(float4*)(out + (size_t)row * C + colb) = o;
    }
  }
}

// ---------------------------------------------------------------------------
// K3: fused l2norm + corr + appearance + motion attention per bt.
// 1024 threads, 16 waves, one 16-row tile per wave (4 waves/SIMD).
// ---------------------------------------------------------------------------
__global__ __launch_bounds__(1024, 1) void fused_attn(
    const bf16* __restrict__ Qg, const bf16* __restrict__ Kg,
    const bf16* __restrict__ Vg, const float* __restrict__ pos,
    bf16* __restrict__ merged) {
  __shared__ __align__(16) bf16 Klds[208 * KW];    // 43,264 B  K tokens x ch
  __shared__ __align__(16) bf16 Vt[96 * VW2];      // 40,704 B  V^T: ch x tok
  __shared__ __align__(16) bf16 corrT[208 * UW];   // 29,952 B  tok x disp(64pad)
  __shared__ float invQ[208];                      //     832 B
  const int bt = blockIdx.x;
  const int tid = threadIdx.x;
  const int w = tid >> 6, lane = tid & 63;
  const int lr = lane & 15, lg = lane >> 4;
  const size_t gbase = (size_t)bt * CHW;

  // ---- P0: staging + invQ ----
  {
    const uint4* kg = (const uint4*)(Kg + gbase);             // 196 rows x 12
    uint4* kl = (uint4*)Klds;                                 // 13 uint4/row
    for (int i = tid; i < 196 * 12; i += 1024) { const int r = i / 12, g = i - r * 12; kl[r * 13 + g] = kg[i]; }
    const uint4 z4 = make_uint4(0u, 0u, 0u, 0u);
    for (int i = tid; i < 12 * 13; i += 1024) { const int r = 196 + i / 13, g = i % 13; kl[r * 13 + g] = z4; }
    const uint* vg = (const uint*)(Vg + gbase);               // 96 x 98 u32
    uint* vl = (uint*)Vt;                                     // 106 u32/row
    for (int i = tid; i < 96 * 98; i += 1024) { const int c = i / 98, g = i - c * 98; vl[c * 106 + g] = vg[i]; }
    for (int i = tid; i < 96 * 8; i += 1024)  { const int c = i / 8, g = 98 + (i & 7); vl[c * 106 + g] = 0u; }
    uint* ct32 = (uint*)corrT;                                // 36 u32/row
    for (int i = tid; i < 208 * 36; i += 1024) {
      const int n = i % 208, up = i / 208;
      const int u0 = 2 * up, u1 = u0 + 1;
      const float p0 = (n < 196 && u0 < 49) ? pos[u0 * 196 + n] : 0.f;
      const float p1 = (n < 196 && u1 < 49) ? pos[u1 * 196 + n] : 0.f;
      ct32[n * 36 + up] = pk2(p0, p1);
    }
    // invQ: per-row inverse norms of Q (rows 0..195)
    if (tid < 208) {
      float s = 0.f;
      if (tid < 196) {
        const uint* qr = (const uint*)(Qg + gbase + (size_t)tid * HD);
#pragma unroll
        for (int g = 0; g < 48; ++g) {
          const uint pk = qr[g];
          const float a = u2f((ushort)(pk & 0xffff));
          const float b = u2f((ushort)(pk >> 16));
          s += a * a + b * b;
        }
      }
      invQ[tid] = 1.f / fmaxf(sqrtf(s), 1e-12f);
    }
  }
  __syncthreads();
  // ---- P0b: normalize K rows in LDS ----
  if (tid < 208) {
    uint* rowp = (uint*)(Klds + tid * KW);   // 48 u32 of data
    float s = 0.f;
#pragma unroll
    for (int g = 0; g < 48; ++g) {
      const uint pk = rowp[g];
      const float a = u2f((ushort)(pk & 0xffff));
      const float b = u2f((ushort)(pk >> 16));
      s += a * a + b * b;
    }
    const float inv = 1.f / fmaxf(sqrtf(s), 1e-12f);
#pragma unroll
    for (int g = 0; g < 48; ++g) {
      const uint pk = rowp[g];
      rowp[g] = pk2(u2f((ushort)(pk & 0xffff)) * inv, u2f((ushort)(pk >> 16)) * inv);
    }
  }
  __syncthreads();

  const int b_ = bt >> 6, head = (bt >> 3) & 7, tt = bt & 7;
  union PW { short8v v; uint u[4]; };
  const int rt = w;                       // one tile per wave
  f32x4 pacc[6];
#pragma unroll
  for (int ct = 0; ct < 6; ++ct) pacc[ct] = (f32x4){0.f, 0.f, 0.f, 0.f};

  // ---- P1: S^T -> scale by invQ -> corr extract -> softmax -> app PV ----
  if (rt < NT) {
    const int rq = (rt * 16 + lr > 195) ? 195 : rt * 16 + lr;
    short8v qf[3];
#pragma unroll
    for (int kc = 0; kc < 3; ++kc)
      qf[kc] = *(const short8v*)(Qg + gbase + (size_t)rq * HD + kc * 32 + lg * 8);
    f32x4 sacc[NT];
#pragma unroll
    for (int mt = 0; mt < NT; ++mt) sacc[mt] = (f32x4){0.f, 0.f, 0.f, 0.f};
    __builtin_amdgcn_s_setprio(1);
#pragma unroll
    for (int kc = 0; kc < 3; ++kc)
#pragma unroll
      for (int mt = 0; mt < NT; ++mt) {
        const short8v kf = *(const short8v*)&Klds[(mt * 16 + lr) * KW + kc * 32 + lg * 8];
        sacc[mt] = __builtin_amdgcn_mfma_f32_16x16x32_bf16(kf, qf[kc], sacc[mt], 0, 0, 0);
      }
    __builtin_amdgcn_s_setprio(0);
    // apply Q normalization (lane-constant: query = rq)
    const float iq = invQ[rq];
#pragma unroll
    for (int mt = 0; mt < NT; ++mt) {
      sacc[mt][0] *= iq; sacc[mt][1] *= iq; sacc[mt][2] *= iq; sacc[mt][3] *= iq;
    }
    // corr extraction (normalized S): query = rt*16+lr, keys = mt*16+lg*4+r
    const int rowg = rt * 16 + lr;
    if (rowg < 196) {
      const int h = rowg / 14, wq = rowg - (rowg / 14) * 14;
      int h2 = 0, w2 = lg * 4;
#pragma unroll
      for (int mt = 0; mt < NT; ++mt) {
        int hh = h2, ww = w2;
#pragma unroll
        for (int r = 0; r < 4; ++r) {
          if (mt < 12 || lg * 4 + r < 4) {
            const int dh = hh - h + 3, dw = ww - wq + 3;
            if (((unsigned)dh < 7u) && ((unsigned)dw < 7u)) {
              bf16* cp = &corrT[rowg * UW + dh * 7 + dw];
              *cp = f2b(b2f(*cp) + sacc[mt][r]);
            }
          }
          if (++ww == 14) { ww = 0; ++hh; }
        }
        w2 += 2; h2 += 1; if (w2 >= 14) { w2 -= 14; h2 += 1; }
      }
    }
    // softmax over keys (0.5 folded)
    float m0 = -1e30f, m1 = -1e30f, m2 = -1e30f, m3 = -1e30f;
#pragma unroll
    for (int mt = 0; mt < 12; ++mt) {
      m0 = fmaxf(m0, sacc[mt][0]); m1 = fmaxf(m1, sacc[mt][1]);
      m2 = fmaxf(m2, sacc[mt][2]); m3 = fmaxf(m3, sacc[mt][3]);
    }
    if (lg == 0) {
      m0 = fmaxf(m0, sacc[12][0]); m1 = fmaxf(m1, sacc[12][1]);
      m2 = fmaxf(m2, sacc[12][2]); m3 = fmaxf(m3, sacc[12][3]);
    }
    float mx = fmaxf(fmaxf(m0, m1), fmaxf(m2, m3));
    mx = fmaxf(mx, __shfl_xor(mx, 16));
    mx = fmaxf(mx, __shfl_xor(mx, 32));
    float s0 = 0.f, s1 = 0.f, s2 = 0.f, s3 = 0.f;
#pragma unroll
    for (int mt = 0; mt < NT; ++mt) {
      const bool dead = (mt == 12) && (lg != 0);
      const float e0 = dead ? 0.f : __expf(sacc[mt][0] - mx);
      const float e1 = dead ? 0.f : __expf(sacc[mt][1] - mx);
      const float e2 = dead ? 0.f : __expf(sacc[mt][2] - mx);
      const float e3 = dead ? 0.f : __expf(sacc[mt][3] - mx);
      sacc[mt][0] = e0; sacc[mt][1] = e1; sacc[mt][2] = e2; sacc[mt][3] = e3;
      s0 += e0; s1 += e1; s2 += e2; s3 += e3;
    }
    float s = (s0 + s1) + (s2 + s3);
    s += __shfl_xor(s, 16); s += __shfl_xor(s, 32);
    const float sc = 0.5f / s;
    PW pf[7];
#pragma unroll
    for (int kb = 0; kb < 7; ++kb) {
      pf[kb].u[0] = pk2(sacc[2 * kb][0] * sc, sacc[2 * kb][1] * sc);
      pf[kb].u[1] = pk2(sacc[2 * kb][2] * sc, sacc[2 * kb][3] * sc);
      if (kb < 6) {
        pf[kb].u[2] = pk2(sacc[2 * kb + 1][0] * sc, sacc[2 * kb + 1][1] * sc);
        pf[kb].u[3] = pk2(sacc[2 * kb + 1][2] * sc, sacc[2 * kb + 1][3] * sc);
      } else { pf[kb].u[2] = 0u; pf[kb].u[3] = 0u; }
    }
    __builtin_amdgcn_s_setprio(1);
#pragma unroll
    for (int ct = 0; ct < 6; ++ct) {
      const int c = ct * 16 + lr;
#pragma unroll
      for (int kb = 0; kb < 7; ++kb) {
        const uint2 lo = *(const uint2*)&Vt[c * VW2 + (2 * kb) * 16 + lg * 4];
        const uint2 hi = (kb < 6) ? *(const uint2*)&Vt[c * VW2 + (2 * kb + 1) * 16 + lg * 4] : lo;
        PW vf; vf.u[0] = lo.x; vf.u[1] = lo.y; vf.u[2] = hi.x; vf.u[3] = hi.y;
        pacc[ct] = __builtin_amdgcn_mfma_f32_16x16x32_bf16(pf[kb].v, vf.v, pacc[ct], 0, 0, 0);
      }
    }
    __builtin_amdgcn_s_setprio(0);
  }
  __syncthreads();

  // ---- P2: M = corrT.corrT^T -> softmax -> PV (+= into pacc) -> store ----
  if (rt < NT) {
    short8v cq[2];
#pragma unroll
    for (int kc = 0; kc < 2; ++kc)
      cq[kc] = *(const short8v*)&corrT[(rt * 16 + lr) * UW + kc * 32 + lg * 8];
    f32x4 macc[NT];
#pragma unroll
    for (int mt = 0; mt < NT; ++mt) macc[mt] = (f32x4){0.f, 0.f, 0.f, 0.f};
    __builtin_amdgcn_s_setprio(1);
#pragma unroll
    for (int kc = 0; kc < 2; ++kc)
#pragma unroll
      for (int mt = 0; mt < NT; ++mt) {
        const short8v ca = *(const short8v*)&corrT[(mt * 16 + lr) * UW + kc * 32 + lg * 8];
        macc[mt] = __builtin_amdgcn_mfma_f32_16x16x32_bf16(ca, cq[kc], macc[mt], 0, 0, 0);
      }
    __builtin_amdgcn_s_setprio(0);
    float m0 = -1e30f, m1 = -1e30f, m2 = -1e30f, m3 = -1e30f;
#pragma unroll
    for (int mt = 0; mt < 12; ++mt) {
      m0 = fmaxf(m0, macc[mt][0]); m1 = fmaxf(m1, macc[mt][1]);
      m2 = fmaxf(m2, macc[mt][2]); m3 = fmaxf(m3, macc[mt][3]);
    }
    if (lg == 0) {
      m0 = fmaxf(m0, macc[12][0]); m1 = fmaxf(m1, macc[12][1]);
      m2 = fmaxf(m2, macc[12][2]); m3 = fmaxf(m3, macc[12][3]);
    }
    float mx = fmaxf(fmaxf(m0, m1), fmaxf(m2, m3));
    mx = fmaxf(mx, __shfl_xor(mx, 16));
    mx = fmaxf(mx, __shfl_xor(mx, 32));
    float s0 = 0.f, s1 = 0.f, s2 = 0.f, s3 = 0.f;
#pragma unroll
    for (int mt = 0; mt < NT; ++mt) {
      const bool dead = (mt == 12) && (lg != 0);
      const float e0 = dead ? 0.f : __expf(macc[mt][0] - mx);
      const float e1 = dead ? 0.f : __expf(macc[mt][1] - mx);
      const float e2 = dead ? 0.f : __expf(macc[mt][2] - mx);
      const float e3 = dead ? 0.f : __expf(macc[mt][3] - mx);
      macc[mt][0] = e0; macc[mt][1] = e1; macc[mt][2] = e2; macc[mt][3] = e3;
      s0 += e0; s1 += e1; s2 += e2; s3 += e3;
    }
    float s = (s0 + s1) + (s2 + s3);
    s += __shfl_xor(s, 16); s += __shfl_xor(s, 32);
    const float sc = 0.5f / s;
    PW pf[7];
#pragma unroll
    for (int kb = 0; kb < 7; ++kb) {
      pf[kb].u[0] = pk2(macc[2 * kb][0] * sc, macc[2 * kb][1] * sc);
      pf[kb].u[1] = pk2(macc[2 * kb][2] * sc, macc[2 * kb][3] * sc);
      if (kb < 6) {
        pf[kb].u[2] = pk2(macc[2 * kb + 1][0] * sc, macc[2 * kb + 1][1] * sc);
        pf[kb].u[3] = pk2(macc[2 * kb + 1][2] * sc, macc[2 * kb + 1][3] * sc);
      } else { pf[kb].u[2] = 0u; pf[kb].u[3] = 0u; }
    }
    __builtin_amdgcn_s_setprio(1);
#pragma unroll
    for (int ct = 0; ct < 6; ++ct) {
      const int c = ct * 16 + lr;
#pragma unroll
      for (int kb = 0; kb < 7; ++kb) {
        const uint2 lo = *(const uint2*)&Vt[c * VW2 + (2 * kb) * 16 + lg * 4];
        const uint2 hi = (kb < 6) ? *(const uint2*)&Vt[c * VW2 + (2 * kb + 1) * 16 + lg * 4] : lo;
        PW vf; vf.u[0] = lo.x; vf.u[1] = lo.y; vf.u[2] = hi.x; vf.u[3] = hi.y;
        pacc[ct] = __builtin_amdgcn_mfma_f32_16x16x32_bf16(pf[kb].v, vf.v, pacc[ct], 0, 0, 0);
      }
    }
    __builtin_amdgcn_s_setprio(0);
    // single merged store: 0.5*(app+motion)
#pragma unroll
    for (int r = 0; r < 4; ++r) {
      const int rowq = rt * 16 + lg * 4 + r;
      if (rowq < 196) {
        const size_t ob = ((size_t)(b_ * NTOK + tt * HW + rowq)) * C + head * HD;
#pragma unroll
        for (int ct = 0; ct < 6; ++ct)
          merged[ob + ct * 16 + lr] = f2b(pacc[ct][r]);
      }
    }
  }
}

}  // namespace

extern "C" void kernel_launch(void* const* d_in, const int* in_sizes, int n_in,
                              void* d_out, int out_size, void* d_ws, size_t ws_size,
                              hipStream_t stream) {
  (void)in_sizes; (void)n_in; (void)out_size; (void)ws_size;
  const float* x      = (const float*)d_in[0];
  const float* w_qkv  = (const float*)d_in[1];
  const float* w_proj = (const float*)d_in[2];
  const float* b_proj = (const float*)d_in[3];
  const float* pos    = (const float*)d_in[4];
  float* out = (float*)d_out;

  char* p = (char*)d_ws;
  bf16* Qb = (bf16*)p;      p += (size_t)BHT * CHW * sizeof(bf16);    // 38.5 MB
  bf16* Kb = (bf16*)p;      p += (size_t)BHT * CHW * sizeof(bf16);    // 38.5 MB
  bf16* Vb = (bf16*)p;      p += (size_t)BHT * CHW * sizeof(bf16);    // 38.5 MB
  bf16* xbm = (bf16*)p;     p += (size_t)NROWS * C * sizeof(bf16);    // 38.5 MB (xb, then merged)
  bf16* wqkvT = (bf16*)p;   p += (size_t)C3 * C * sizeof(bf16);       // 3.5 MB
  bf16* wprojT = (bf16*)p;  p += (size_t)C * C * sizeof(bf16);        // 1.2 MB
  // total ws: ~159 MB

  conv_to_bf16<<<(NROWS * C / 8 + 255) / 256, 256, 0, stream>>>(x, xbm, NROWS * C / 8);
  transpose_to_bf16<<<dim3(C3 / 64, C / 64), 256, 0, stream>>>(w_qkv, wqkvT, C, C3);
  transpose_to_bf16<<<dim3(C / 64, C / 64), 256, 0, stream>>>(w_proj, wprojT, C, C);
  gemm_qkv_mfma<<<3528, 256, 0, stream>>>(xbm, wqkvT, Qb, Kb, Vb);
  fused_attn<<<BHT, 1024, 0, stream>>>(Qb, Kb, Vb, pos, xbm /*merged*/);
  gemm_proj_mfma<<<1176, 256, 0, stream>>>(xbm, wprojT, b_proj, out);
}

// Round 13
// 285.977 us; speedup vs baseline: 1.2200x; 1.0345x over previous
//
#include <hip/hip_runtime.h>
#include <hip/hip_bf16.h>

namespace {

constexpr int T = 8, HW = 196;
constexpr int C = 768, NH = 8, HD = 96;
constexpr int NTOK = 1568;
constexpr int BHT = 1024;          // B*NH*T
constexpr int C3 = 2304;           // 3*C
constexpr int CHW = HD * HW;       // 18816
constexpr int NROWS = 25088;       // B*NTOK
constexpr int NT = 13;             // 16-row tiles covering 208 >= 196
constexpr int KW = 104;            // Klds row stride (bf16)
constexpr int VW2 = 212;           // Vt row stride (bf16)
constexpr int TSZ = 128 * 64;      // one GEMM LDS tile (elems)

using bf16 = __hip_bfloat16;
typedef __attribute__((ext_vector_type(8))) short short8v;  // 8 x bf16 frag
typedef __attribute__((ext_vector_type(4))) float f32x4;

__device__ __forceinline__ float b2f(bf16 h) { return __bfloat162float(h); }
__device__ __forceinline__ bf16 f2b(float f) { return __float2bfloat16(f); }
__device__ __forceinline__ float u2f(ushort u) {
  union { ushort u[2]; float f; } x; x.u[0] = 0; x.u[1] = u; return x.f;
}
__device__ __forceinline__ ushort b2u(bf16 h) { union { bf16 b; ushort u; } x; x.b = h; return x.u; }
__device__ __forceinline__ uint pk2(float lo, float hi) {
  return ((uint)b2u(f2b(hi)) << 16) | (uint)b2u(f2b(lo));
}
__device__ __forceinline__ void gload_lds16(const bf16* g, bf16* l) {
  __builtin_amdgcn_global_load_lds(
      (const __attribute__((address_space(1))) unsigned int*)g,
      (__attribute__((address_space(3))) unsigned int*)l, 16, 0, 0);
}

// ---------------------------------------------------------------------------
// K0a: elementwise f32 -> bf16 (8 elems / thread)
// ---------------------------------------------------------------------------
__global__ __launch_bounds__(256) void conv_to_bf16(
    const float* __restrict__ X, bf16* __restrict__ Y, int n8) {
  const int i = blockIdx.x * 256 + threadIdx.x;
  if (i >= n8) return;
  const float4 a = ((const float4*)X)[i * 2];
  const float4 b = ((const float4*)X)[i * 2 + 1];
  uint4 o;
  o.x = pk2(a.x, a.y); o.y = pk2(a.z, a.w);
  o.z = pk2(b.x, b.y); o.w = pk2(b.z, b.w);
  ((uint4*)Y)[i] = o;
}

// ---------------------------------------------------------------------------
// K0b: W [rows][cols] f32 -> Wt [cols][rows] bf16, 64x64 LDS tiles.
// ---------------------------------------------------------------------------
__global__ __launch_bounds__(256) void transpose_to_bf16(
    const float* __restrict__ W, bf16* __restrict__ Wt, int rows, int cols) {
  __shared__ __align__(16) bf16 Lt[64][72];
  const int r0 = blockIdx.y * 64, c0 = blockIdx.x * 64;
  const int tid = threadIdx.x;
  const int r = tid >> 2, q = (tid & 3) * 16;
  const float* src = W + (size_t)(r0 + r) * cols + c0 + q;
#pragma unroll
  for (int i = 0; i < 16; i += 4) {
    const float4 v = *(const float4*)(src + i);
    Lt[q + i + 0][r] = f2b(v.x);
    Lt[q + i + 1][r] = f2b(v.y);
    Lt[q + i + 2][r] = f2b(v.z);
    Lt[q + i + 3][r] = f2b(v.w);
  }
  __syncthreads();
  const int c = tid >> 2, kc = (tid & 3) * 16;
  uint4* dst = (uint4*)(Wt + (size_t)(c0 + c) * rows + r0 + kc);
  const uint4* srcl = (const uint4*)(&Lt[c][kc]);
  dst[0] = srcl[0];
  dst[1] = srcl[1];
}

// ---------------------------------------------------------------------------
// Shared 128x128xK=768 MFMA core, single-buffered (32 KB) + T2 XOR swizzle.
// ---------------------------------------------------------------------------
__device__ __forceinline__ void gemm128_core(
    const bf16* __restrict__ A, const bf16* __restrict__ Bt,
    int rt, int ct, bf16* As, bf16* Bs, f32x4 acc[4][4]) {
  const int tid = threadIdx.x;
  const int w = tid >> 6, lane = tid & 63;
  const int lr = lane & 15, lg = lane >> 4;
  const int wr = w >> 1, wc = w & 1;
  const int crow = (lane >> 3);                       // row within 8-row chunk
  const int cole = ((lane & 7) ^ crow) << 3;          // pre-swizzled src elem
#pragma unroll
  for (int i = 0; i < 4; ++i)
#pragma unroll
    for (int j = 0; j < 4; ++j) acc[i][j] = (f32x4){0.f, 0.f, 0.f, 0.f};

  for (int kt = 0; kt < 12; ++kt) {
    const int k0 = kt * 64;
    __syncthreads();
#pragma unroll
    for (int i = 0; i < 4; ++i) {
      const int chunk = w * 4 + i;                    // 16 chunks of 8 rows
      const int row = chunk * 8 + crow;
      gload_lds16(A + (size_t)(rt + row) * 768 + k0 + cole, As + chunk * 512);
      gload_lds16(Bt + (size_t)(ct + row) * 768 + k0 + cole, Bs + chunk * 512);
    }
    __syncthreads();
#pragma unroll
    for (int kc = 0; kc < 2; ++kc) {
      const int roff = ((kc * 4 + lg) ^ (lr & 7)) << 3;  // swizzled read elem
      short8v xa[4], wb[4];
#pragma unroll
      for (int f = 0; f < 4; ++f) {
        xa[f] = *(const short8v*)(As + (wr * 64 + f * 16 + lr) * 64 + roff);
        wb[f] = *(const short8v*)(Bs + (wc * 64 + f * 16 + lr) * 64 + roff);
      }
#pragma unroll
      for (int cj = 0; cj < 4; ++cj)
#pragma unroll
        for (int ri = 0; ri < 4; ++ri)
          acc[cj][ri] = __builtin_amdgcn_mfma_f32_16x16x32_bf16(wb[cj], xa[ri], acc[cj][ri], 0, 0, 0);
    }
  }
}

// ---------------------------------------------------------------------------
// K1: QKV GEMM, scatter epilogue to Q / K(shifted) / V (all unnormalized).
// ---------------------------------------------------------------------------
__global__ __launch_bounds__(256, 3) void gemm_qkv_mfma(
    const bf16* __restrict__ A, const bf16* __restrict__ Bt,
    bf16* __restrict__ Qo, bf16* __restrict__ Ko, bf16* __restrict__ Vo) {
  __shared__ __align__(16) bf16 As[TSZ];
  __shared__ __align__(16) bf16 Bs[TSZ];
  const int id = blockIdx.x;
  const int sw = (id & 7) * 441 + (id >> 3);   // 3528 = 8 * 441 (bijective)
  const int cti = sw % 18, rti = sw / 18;
  const int ct = cti * 128, rt = rti * 128;
  const int tid = threadIdx.x;
  const int w = tid >> 6, lane = tid & 63;
  const int lr = lane & 15, lg = lane >> 4;
  const int wr = w >> 1, wc = w & 1;

  f32x4 acc[4][4];
  gemm128_core(A, Bt, rt, ct, As, Bs, acc);

  const int s = cti / 6;
#pragma unroll
  for (int ri = 0; ri < 4; ++ri) {
    const int row = rt + wr * 64 + ri * 16 + lr;
    const int b_ = row / NTOK, n = row % NTOK;
    const int t = n / HW, hw = n % HW;
#pragma unroll
    for (int cj = 0; cj < 4; ++cj) {
      const int colb = ct + wc * 64 + cj * 16 + lg * 4;
      const int rem = colb - s * C;
      const int head = rem / HD, chb = rem - head * HD;
      const int bh = b_ * NH + head;
      if (s == 0) {
        uint2 pk;
        pk.x = pk2(acc[cj][ri][0], acc[cj][ri][1]);
        pk.y = pk2(acc[cj][ri][2], acc[cj][ri][3]);
        *(uint2*)(Qo + (size_t)(bh * T + t) * CHW + hw * HD + chb) = pk;
      } else if (s == 1) {
        uint2 pk;
        pk.x = pk2(acc[cj][ri][0], acc[cj][ri][1]);
        pk.y = pk2(acc[cj][ri][2], acc[cj][ri][3]);
        if (t >= 1)
          *(uint2*)(Ko + (size_t)(bh * T + t - 1) * CHW + hw * HD + chb) = pk;
        if (t == T - 1)
          *(uint2*)(Ko + (size_t)(bh * T + t) * CHW + hw * HD + chb) = pk;
      } else {
#pragma unroll
        for (int j = 0; j < 4; ++j)
          Vo[(size_t)(bh * T + t) * CHW + (chb + j) * HW + hw] = f2b(acc[cj][ri][j]);
      }
    }
  }
}

// ---------------------------------------------------------------------------
// K4: proj GEMM + bias -> out f32.
// ---------------------------------------------------------------------------
__global__ __launch_bounds__(256, 3) void gemm_proj_mfma(
    const bf16* __restrict__ A, const bf16* __restrict__ Bt,
    const float* __restrict__ bias, float* __restrict__ out) {
  __shared__ __align__(16) bf16 As[TSZ];
  __shared__ __align__(16) bf16 Bs[TSZ];
  const int id = blockIdx.x;
  const int sw = (id & 7) * 147 + (id >> 3);   // 1176 = 8 * 147 (bijective)
  const int cti = sw % 6, rti = sw / 6;
  const int ct = cti * 128, rt = rti * 128;
  const int tid = threadIdx.x;
  const int w = tid >> 6, lane = tid & 63;
  const int lr = lane & 15, lg = lane >> 4;
  const int wr = w >> 1, wc = w & 1;

  f32x4 acc[4][4];
  gemm128_core(A, Bt, rt, ct, As, Bs, acc);

#pragma unroll
  for (int ri = 0; ri < 4; ++ri) {
    const int row = rt + wr * 64 + ri * 16 + lr;
#pragma unroll
    for (int cj = 0; cj < 4; ++cj) {
      const int colb = ct + wc * 64 + cj * 16 + lg * 4;
      const float4 bv = *(const float4*)(bias + colb);
      float4 o;
      o.x = acc[cj][ri][0] + bv.x;
      o.y = acc[cj][ri][1] + bv.y;
      o.z = acc[cj][ri][2] + bv.z;
      o.w = acc[cj][ri][3] + bv.w;
      *(float4*)(out + (size_t)row * C + colb) = o;
    }
  }
}

// ---------------------------------------------------------------------------
// K3: fused l2norm + corr + appearance + motion attention per bt.
// 1024 threads, 16 waves, one 16-row tile per wave.
// corrT: [208][64] bf16, XOR block-swizzle (block ^= row&7) -> conflict-free
// MFMA reads. Extraction = pure stores (S only); pos added by a parallel
// sweep between P1 and P2 (no serialized LDS RMW chain).
// ---------------------------------------------------------------------------
__global__ __launch_bounds__(1024, 1) void fused_attn(
    const bf16* __restrict__ Qg, const bf16* __restrict__ Kg,
    const bf16* __restrict__ Vg, const float* __restrict__ pos,
    bf16* __restrict__ merged) {
  __shared__ __align__(16) bf16 Klds[208 * KW];    // 43,264 B  K tokens x ch
  __shared__ __align__(16) bf16 Vt[96 * VW2];      // 40,704 B  V^T: ch x tok
  __shared__ __align__(16) bf16 corrT[208 * 64];   // 26,624 B  tok x disp(swz)
  __shared__ float invQ[208];                      //     832 B
  const int bt = blockIdx.x;
  const int tid = threadIdx.x;
  const int w = tid >> 6, lane = tid & 63;
  const int lr = lane & 15, lg = lane >> 4;
  const size_t gbase = (size_t)bt * CHW;

  // ---- P0: staging + zero corrT + invQ (4 threads/row) ----
  {
    const uint4* kg = (const uint4*)(Kg + gbase);             // 196 rows x 12
    uint4* kl = (uint4*)Klds;                                 // 13 uint4/row
    for (int i = tid; i < 196 * 12; i += 1024) { const int r = i / 12, g = i - r * 12; kl[r * 13 + g] = kg[i]; }
    const uint4 z4 = make_uint4(0u, 0u, 0u, 0u);
    for (int i = tid; i < 12 * 13; i += 1024) { const int r = 196 + i / 13, g = i % 13; kl[r * 13 + g] = z4; }
    const uint* vg = (const uint*)(Vg + gbase);               // 96 x 98 u32
    uint* vl = (uint*)Vt;                                     // 106 u32/row
    for (int i = tid; i < 96 * 98; i += 1024) { const int c = i / 98, g = i - c * 98; vl[c * 106 + g] = vg[i]; }
    for (int i = tid; i < 96 * 8; i += 1024)  { const int c = i / 8, g = 98 + (i & 7); vl[c * 106 + g] = 0u; }
    uint4* cz = (uint4*)corrT;                                // 1664 uint4
    for (int i = tid; i < 1664; i += 1024) cz[i] = z4;
    // invQ: 4 threads per row, shfl-reduce
    if (tid < 832) {
      const int row = tid >> 2, sub = tid & 3;
      float s = 0.f;
      if (row < 196) {
        const uint4* qr = (const uint4*)(Qg + gbase + (size_t)row * HD) + sub * 3;
#pragma unroll
        for (int g = 0; g < 3; ++g) {
          const uint4 v = qr[g];
          const uint uu[4] = {v.x, v.y, v.z, v.w};
#pragma unroll
          for (int q = 0; q < 4; ++q) {
            const float a = u2f((ushort)(uu[q] & 0xffff));
            const float b = u2f((ushort)(uu[q] >> 16));
            s += a * a + b * b;
          }
        }
      }
      s += __shfl_xor(s, 1); s += __shfl_xor(s, 2);
      if (sub == 0) invQ[row] = 1.f / fmaxf(sqrtf(s), 1e-12f);
    }
  }
  __syncthreads();
  // ---- P0b: normalize K rows in LDS (4 threads/row) ----
  if (tid < 832) {
    const int row = tid >> 2, sub = tid & 3;
    uint* rowp = (uint*)(Klds + row * KW) + sub * 12;
    float s = 0.f;
#pragma unroll
    for (int g = 0; g < 12; ++g) {
      const uint pk = rowp[g];
      const float a = u2f((ushort)(pk & 0xffff));
      const float b = u2f((ushort)(pk >> 16));
      s += a * a + b * b;
    }
    s += __shfl_xor(s, 1); s += __shfl_xor(s, 2);
    const float inv = 1.f / fmaxf(sqrtf(s), 1e-12f);
#pragma unroll
    for (int g = 0; g < 12; ++g) {
      const uint pk = rowp[g];
      rowp[g] = pk2(u2f((ushort)(pk & 0xffff)) * inv, u2f((ushort)(pk >> 16)) * inv);
    }
  }
  __syncthreads();

  const int b_ = bt >> 6, head = (bt >> 3) & 7, tt = bt & 7;
  union PW { short8v v; uint u[4]; };
  const int rt = w;                       // one tile per wave
  f32x4 pacc[6];
#pragma unroll
  for (int ct = 0; ct < 6; ++ct) pacc[ct] = (f32x4){0.f, 0.f, 0.f, 0.f};

  // ---- P1: S^T -> scale by invQ -> corr store -> softmax -> app PV ----
  if (rt < NT) {
    const int rq = (rt * 16 + lr > 195) ? 195 : rt * 16 + lr;
    short8v qf[3];
#pragma unroll
    for (int kc = 0; kc < 3; ++kc)
      qf[kc] = *(const short8v*)(Qg + gbase + (size_t)rq * HD + kc * 32 + lg * 8);
    f32x4 sacc[NT];
#pragma unroll
    for (int mt = 0; mt < NT; ++mt) sacc[mt] = (f32x4){0.f, 0.f, 0.f, 0.f};
    __builtin_amdgcn_s_setprio(1);
#pragma unroll
    for (int kc = 0; kc < 3; ++kc)
#pragma unroll
      for (int mt = 0; mt < NT; ++mt) {
        const short8v kf = *(const short8v*)&Klds[(mt * 16 + lr) * KW + kc * 32 + lg * 8];
        sacc[mt] = __builtin_amdgcn_mfma_f32_16x16x32_bf16(kf, qf[kc], sacc[mt], 0, 0, 0);
      }
    __builtin_amdgcn_s_setprio(0);
    // apply Q normalization (lane-constant: query = rq)
    const float iq = invQ[rq];
#pragma unroll
    for (int mt = 0; mt < NT; ++mt) {
      sacc[mt][0] *= iq; sacc[mt][1] *= iq; sacc[mt][2] *= iq; sacc[mt][3] *= iq;
    }
    // corr extraction: PURE STORES of S into swizzled corrT (pos added later)
    const int rowg = rt * 16 + lr;
    if (rowg < 196) {
      const int h = rowg / 14, wq = rowg - (rowg / 14) * 14;
      bf16* crow = corrT + rowg * 64;
      const int rsw = rowg & 7;
      int h2 = 0, w2 = lg * 4;
#pragma unroll
      for (int mt = 0; mt < NT; ++mt) {
        int hh = h2, ww = w2;
#pragma unroll
        for (int r = 0; r < 4; ++r) {
          if (mt < 12 || lg * 4 + r < 4) {
            const int dh = hh - h + 3, dw = ww - wq + 3;
            if (((unsigned)dh < 7u) && ((unsigned)dw < 7u)) {
              const int u = dh * 7 + dw;
              crow[(((u >> 3) ^ rsw) << 3) + (u & 7)] = f2b(sacc[mt][r]);
            }
          }
          if (++ww == 14) { ww = 0; ++hh; }
        }
        w2 += 2; h2 += 1; if (w2 >= 14) { w2 -= 14; h2 += 1; }
      }
    }
    // softmax over keys (0.5 folded)
    float m0 = -1e30f, m1 = -1e30f, m2 = -1e30f, m3 = -1e30f;
#pragma unroll
    for (int mt = 0; mt < 12; ++mt) {
      m0 = fmaxf(m0, sacc[mt][0]); m1 = fmaxf(m1, sacc[mt][1]);
      m2 = fmaxf(m2, sacc[mt][2]); m3 = fmaxf(m3, sacc[mt][3]);
    }
    if (lg == 0) {
      m0 = fmaxf(m0, sacc[12][0]); m1 = fmaxf(m1, sacc[12][1]);
      m2 = fmaxf(m2, sacc[12][2]); m3 = fmaxf(m3, sacc[12][3]);
    }
    float mx = fmaxf(fmaxf(m0, m1), fmaxf(m2, m3));
    mx = fmaxf(mx, __shfl_xor(mx, 16));
    mx = fmaxf(mx, __shfl_xor(mx, 32));
    float s0 = 0.f, s1 = 0.f, s2 = 0.f, s3 = 0.f;
#pragma unroll
    for (int mt = 0; mt < NT; ++mt) {
      const bool dead = (mt == 12) && (lg != 0);
      const float e0 = dead ? 0.f : __expf(sacc[mt][0] - mx);
      const float e1 = dead ? 0.f : __expf(sacc[mt][1] - mx);
      const float e2 = dead ? 0.f : __expf(sacc[mt][2] - mx);
      const float e3 = dead ? 0.f : __expf(sacc[mt][3] - mx);
      sacc[mt][0] = e0; sacc[mt][1] = e1; sacc[mt][2] = e2; sacc[mt][3] = e3;
      s0 += e0; s1 += e1; s2 += e2; s3 += e3;
    }
    float s = (s0 + s1) + (s2 + s3);
    s += __shfl_xor(s, 16); s += __shfl_xor(s, 32);
    const float sc = 0.5f / s;
    PW pf[7];
#pragma unroll
    for (int kb = 0; kb < 7; ++kb) {
      pf[kb].u[0] = pk2(sacc[2 * kb][0] * sc, sacc[2 * kb][1] * sc);
      pf[kb].u[1] = pk2(sacc[2 * kb][2] * sc, sacc[2 * kb][3] * sc);
      if (kb < 6) {
        pf[kb].u[2] = pk2(sacc[2 * kb + 1][0] * sc, sacc[2 * kb + 1][1] * sc);
        pf[kb].u[3] = pk2(sacc[2 * kb + 1][2] * sc, sacc[2 * kb + 1][3] * sc);
      } else { pf[kb].u[2] = 0u; pf[kb].u[3] = 0u; }
    }
    __builtin_amdgcn_s_setprio(1);
#pragma unroll
    for (int ct = 0; ct < 6; ++ct) {
      const int c = ct * 16 + lr;
#pragma unroll
      for (int kb = 0; kb < 7; ++kb) {
        const uint2 lo = *(const uint2*)&Vt[c * VW2 + (2 * kb) * 16 + lg * 4];
        const uint2 hi = (kb < 6) ? *(const uint2*)&Vt[c * VW2 + (2 * kb + 1) * 16 + lg * 4] : lo;
        PW vf; vf.u[0] = lo.x; vf.u[1] = lo.y; vf.u[2] = hi.x; vf.u[3] = hi.y;
        pacc[ct] = __builtin_amdgcn_mfma_f32_16x16x32_bf16(pf[kb].v, vf.v, pacc[ct], 0, 0, 0);
      }
    }
    __builtin_amdgcn_s_setprio(0);
  }
  __syncthreads();

  // ---- pos sweep: corrT += pos (parallel, coalesced) ----
  {
    uint* ct32 = (uint*)corrT;
    for (int i = tid; i < 208 * 25; i += 1024) {
      const int n = i % 208, wp = i / 208;   // wp in [0,25): u0=2wp<=48
      if (n < 196) {
        const int u0 = 2 * wp, u1 = u0 + 1;
        const int ad = n * 32 + (((wp >> 2) ^ (n & 7)) << 2) + (wp & 3);
        const uint pk = ct32[ad];
        const float v0 = u2f((ushort)(pk & 0xffff)) + pos[u0 * 196 + n];
        const float v1 = u2f((ushort)(pk >> 16)) + (u1 < 49 ? pos[u1 * 196 + n] : 0.f);
        ct32[ad] = pk2(v0, v1);
      }
    }
  }
  __syncthreads();

  // ---- P2: M = corrT.corrT^T -> softmax -> PV (+= into pacc) -> store ----
  if (rt < NT) {
    const int csw = lr & 7;
    short8v cq[2];
#pragma unroll
    for (int kc = 0; kc < 2; ++kc)
      cq[kc] = *(const short8v*)&corrT[(rt * 16 + lr) * 64 + (((kc * 4 + lg) ^ csw) << 3)];
    f32x4 macc[NT];
#pragma unroll
    for (int mt = 0; mt < NT; ++mt) macc[mt] = (f32x4){0.f, 0.f, 0.f, 0.f};
    __builtin_amdgcn_s_setprio(1);
#pragma unroll
    for (int kc = 0; kc < 2; ++kc)
#pragma unroll
      for (int mt = 0; mt < NT; ++mt) {
        const short8v ca = *(const short8v*)&corrT[(mt * 16 + lr) * 64 + (((kc * 4 + lg) ^ csw) << 3)];
        macc[mt] = __builtin_amdgcn_mfma_f32_16x16x32_bf16(ca, cq[kc], macc[mt], 0, 0, 0);
      }
    __builtin_amdgcn_s_setprio(0);
    float m0 = -1e30f, m1 = -1e30f, m2 = -1e30f, m3 = -1e30f;
#pragma unroll
    for (int mt = 0; mt < 12; ++mt) {
      m0 = fmaxf(m0, macc[mt][0]); m1 = fmaxf(m1, macc[mt][1]);
      m2 = fmaxf(m2, macc[mt][2]); m3 = fmaxf(m3, macc[mt][3]);
    }
    if (lg == 0) {
      m0 = fmaxf(m0, macc[12][0]); m1 = fmaxf(m1, macc[12][1]);
      m2 = fmaxf(m2, macc[12][2]); m3 = fmaxf(m3, macc[12][3]);
    }
    float mx = fmaxf(fmaxf(m0, m1), fmaxf(m2, m3));
    mx = fmaxf(mx, __shfl_xor(mx, 16));
    mx = fmaxf(mx, __shfl_xor(mx, 32));
    float s0 = 0.f, s1 = 0.f, s2 = 0.f, s3 = 0.f;
#pragma unroll
    for (int mt = 0; mt < NT; ++mt) {
      const bool dead = (mt == 12) && (lg != 0);
      const float e0 = dead ? 0.f : __expf(macc[mt][0] - mx);
      const float e1 = dead ? 0.f : __expf(macc[mt][1] - mx);
      const float e2 = dead ? 0.f : __expf(macc[mt][2] - mx);
      const float e3 = dead ? 0.f : __expf(macc[mt][3] - mx);
      macc[mt][0] = e0; macc[mt][1] = e1; macc[mt][2] = e2; macc[mt][3] = e3;
      s0 += e0; s1 += e1; s2 += e2; s3 += e3;
    }
    float s = (s0 + s1) + (s2 + s3);
    s += __shfl_xor(s, 16); s += __shfl_xor(s, 32);
    const float sc = 0.5f / s;
    PW pf[7];
#pragma unroll
    for (int kb = 0; kb < 7; ++kb) {
      pf[kb].u[0] = pk2(macc[2 * kb][0] * sc, macc[2 * kb][1] * sc);
      pf[kb].u[1] = pk2(macc[2 * kb][2] * sc, macc[2 * kb][3] * sc);
      if (kb < 6) {
        pf[kb].u[2] = pk2(macc[2 * kb + 1][0] * sc, macc[2 * kb + 1][1] * sc);
        pf[kb].u[3] = pk2(macc[2 * kb + 1][2] * sc, macc[2 * kb + 1][3] * sc);
      } else { pf[kb].u[2] = 0u; pf[kb].u[3] = 0u; }
    }
    __builtin_amdgcn_s_setprio(1);
#pragma unroll
    for (int ct = 0; ct < 6; ++ct) {
      const int c = ct * 16 + lr;
#pragma unroll
      for (int kb = 0; kb < 7; ++kb) {
        const uint2 lo = *(const uint2*)&Vt[c * VW2 + (2 * kb) * 16 + lg * 4];
        const uint2 hi = (kb < 6) ? *(const uint2*)&Vt[c * VW2 + (2 * kb + 1) * 16 + lg * 4] : lo;
        PW vf; vf.u[0] = lo.x; vf.u[1] = lo.y; vf.u[2] = hi.x; vf.u[3] = hi.y;
        pacc[ct] = __builtin_amdgcn_mfma_f32_16x16x32_bf16(pf[kb].v, vf.v, pacc[ct], 0, 0, 0);
      }
    }
    __builtin_amdgcn_s_setprio(0);
    // single merged store: 0.5*(app+motion)
#pragma unroll
    for (int r = 0; r < 4; ++r) {
      const int rowq = rt * 16 + lg * 4 + r;
      if (rowq < 196) {
        const size_t ob = ((size_t)(b_ * NTOK + tt * HW + rowq)) * C + head * HD;
#pragma unroll
        for (int ct = 0; ct < 6; ++ct)
          merged[ob + ct * 16 + lr] = f2b(pacc[ct][r]);
      }
    }
  }
}

}  // namespace

extern "C" void kernel_launch(void* const* d_in, const int* in_sizes, int n_in,
                              void* d_out, int out_size, void* d_ws, size_t ws_size,
                              hipStream_t stream) {
  (void)in_sizes; (void)n_in; (void)out_size; (void)ws_size;
  const float* x      = (const float*)d_in[0];
  const float* w_qkv  = (const float*)d_in[1];
  const float* w_proj = (const float*)d_in[2];
  const float* b_proj = (const float*)d_in[3];
  const float* pos    = (const float*)d_in[4];
  float* out = (float*)d_out;

  char* p = (char*)d_ws;
  bf16* Qb = (bf16*)p;      p += (size_t)BHT * CHW * sizeof(bf16);    // 38.5 MB
  bf16* Kb = (bf16*)p;      p += (size_t)BHT * CHW * sizeof(bf16);    // 38.5 MB
  bf16* Vb = (bf16*)p;      p += (size_t)BHT * CHW * sizeof(bf16);    // 38.5 MB
  bf16* xbm = (bf16*)p;     p += (size_t)NROWS * C * sizeof(bf16);    // 38.5 MB (xb, then merged)
  bf16* wqkvT = (bf16*)p;   p += (size_t)C3 * C * sizeof(bf16);       // 3.5 MB
  bf16* wprojT = (bf16*)p;  p += (size_t)C * C * sizeof(bf16);        // 1.2 MB
  // total ws: ~159 MB

  conv_to_bf16<<<(NROWS * C / 8 + 255) / 256, 256, 0, stream>>>(x, xbm, NROWS * C / 8);
  transpose_to_bf16<<<dim3(C3 / 64, C / 64), 256, 0, stream>>>(w_qkv, wqkvT, C, C3);
  transpose_to_bf16<<<dim3(C / 64, C / 64), 256, 0, stream>>>(w_proj, wprojT, C, C);
  gemm_qkv_mfma<<<3528, 256, 0, stream>>>(xbm, wqkvT, Qb, Kb, Vb);
  fused_attn<<<BHT, 1024, 0, stream>>>(Qb, Kb, Vb, pos, xbm /*merged*/);
  gemm_proj_mfma<<<1176, 256, 0, stream>>>(xbm, wprojT, b_proj, out);
}

// Round 14
// 279.779 us; speedup vs baseline: 1.2470x; 1.0222x over previous
//
#include <hip/hip_runtime.h>
#include <hip/hip_bf16.h>

namespace {

constexpr int T = 8, HW = 196;
constexpr int C = 768, NH = 8, HD = 96;
constexpr int NTOK = 1568;
constexpr int BHT = 1024;          // B*NH*T
constexpr int C3 = 2304;           // 3*C
constexpr int CHW = HD * HW;       // 18816
constexpr int NROWS = 25088;       // B*NTOK
constexpr int NT = 13;             // 16-row tiles covering 208 >= 196
constexpr int KW = 104;            // Klds row stride (bf16)
constexpr int VW3 = 232;           // Vt row stride (bf16), packed sigma layout
constexpr int TSZ = 128 * 64;      // one GEMM LDS tile (elems)

using bf16 = __hip_bfloat16;
typedef __attribute__((ext_vector_type(8))) short short8v;  // 8 x bf16 frag
typedef __attribute__((ext_vector_type(4))) float f32x4;

__device__ __forceinline__ float b2f(bf16 h) { return __bfloat162float(h); }
__device__ __forceinline__ bf16 f2b(float f) { return __float2bfloat16(f); }
__device__ __forceinline__ float u2f(ushort u) {
  union { ushort u[2]; float f; } x; x.u[0] = 0; x.u[1] = u; return x.f;
}
__device__ __forceinline__ ushort b2u(bf16 h) { union { bf16 b; ushort u; } x; x.b = h; return x.u; }
__device__ __forceinline__ uint pk2(float lo, float hi) {
  return ((uint)b2u(f2b(hi)) << 16) | (uint)b2u(f2b(lo));
}
__device__ __forceinline__ void gload_lds16(const bf16* g, bf16* l) {
  __builtin_amdgcn_global_load_lds(
      (const __attribute__((address_space(1))) unsigned int*)g,
      (__attribute__((address_space(3))) unsigned int*)l, 16, 0, 0);
}

// ---------------------------------------------------------------------------
// K0: merged prep — conv x->bf16 (blocks [0,9408)), transpose w_qkv
// (blocks [9408,9840)), transpose w_proj (blocks [9840,9984)).
// ---------------------------------------------------------------------------
__global__ __launch_bounds__(256) void prep(
    const float* __restrict__ X, bf16* __restrict__ Y,
    const float* __restrict__ Wqkv, bf16* __restrict__ WqkvT,
    const float* __restrict__ Wproj, bf16* __restrict__ WprojT) {
  __shared__ __align__(16) bf16 Lt[64][72];
  const int id = blockIdx.x;
  const int tid = threadIdx.x;
  if (id < 9408) {
    const int i = id * 256 + tid;
    const float4 a = ((const float4*)X)[i * 2];
    const float4 b = ((const float4*)X)[i * 2 + 1];
    uint4 o;
    o.x = pk2(a.x, a.y); o.y = pk2(a.z, a.w);
    o.z = pk2(b.x, b.y); o.w = pk2(b.z, b.w);
    ((uint4*)Y)[i] = o;
    return;
  }
  const bool qkv = (id < 9840);
  const int lid = qkv ? id - 9408 : id - 9840;
  const int nbx = qkv ? 36 : 12;
  const int cols = qkv ? C3 : C;
  const float* W = qkv ? Wqkv : Wproj;
  bf16* Wt = qkv ? WqkvT : WprojT;
  const int c0 = (lid % nbx) * 64, r0 = (lid / nbx) * 64;
  const int r = tid >> 2, q = (tid & 3) * 16;
  const float* src = W + (size_t)(r0 + r) * cols + c0 + q;
#pragma unroll
  for (int i = 0; i < 16; i += 4) {
    const float4 v = *(const float4*)(src + i);
    Lt[q + i + 0][r] = f2b(v.x);
    Lt[q + i + 1][r] = f2b(v.y);
    Lt[q + i + 2][r] = f2b(v.z);
    Lt[q + i + 3][r] = f2b(v.w);
  }
  __syncthreads();
  const int c = tid >> 2, kc = (tid & 3) * 16;
  uint4* dst = (uint4*)(Wt + (size_t)(c0 + c) * C + r0 + kc);
  const uint4* srcl = (const uint4*)(&Lt[c][kc]);
  dst[0] = srcl[0];
  dst[1] = srcl[1];
}

// ---------------------------------------------------------------------------
// Shared 128x128xK=768 MFMA core, single-buffered (32 KB) + T2 XOR swizzle.
// ---------------------------------------------------------------------------
__device__ __forceinline__ void gemm128_core(
    const bf16* __restrict__ A, const bf16* __restrict__ Bt,
    int rt, int ct, bf16* As, bf16* Bs, f32x4 acc[4][4]) {
  const int tid = threadIdx.x;
  const int w = tid >> 6, lane = tid & 63;
  const int lr = lane & 15, lg = lane >> 4;
  const int wr = w >> 1, wc = w & 1;
  const int crow = (lane >> 3);                       // row within 8-row chunk
  const int cole = ((lane & 7) ^ crow) << 3;          // pre-swizzled src elem
#pragma unroll
  for (int i = 0; i < 4; ++i)
#pragma unroll
    for (int j = 0; j < 4; ++j) acc[i][j] = (f32x4){0.f, 0.f, 0.f, 0.f};

  for (int kt = 0; kt < 12; ++kt) {
    const int k0 = kt * 64;
    __syncthreads();
#pragma unroll
    for (int i = 0; i < 4; ++i) {
      const int chunk = w * 4 + i;                    // 16 chunks of 8 rows
      const int row = chunk * 8 + crow;
      gload_lds16(A + (size_t)(rt + row) * 768 + k0 + cole, As + chunk * 512);
      gload_lds16(Bt + (size_t)(ct + row) * 768 + k0 + cole, Bs + chunk * 512);
    }
    __syncthreads();
#pragma unroll
    for (int kc = 0; kc < 2; ++kc) {
      const int roff = ((kc * 4 + lg) ^ (lr & 7)) << 3;  // swizzled read elem
      short8v xa[4], wb[4];
#pragma unroll
      for (int f = 0; f < 4; ++f) {
        xa[f] = *(const short8v*)(As + (wr * 64 + f * 16 + lr) * 64 + roff);
        wb[f] = *(const short8v*)(Bs + (wc * 64 + f * 16 + lr) * 64 + roff);
      }
#pragma unroll
      for (int cj = 0; cj < 4; ++cj)
#pragma unroll
        for (int ri = 0; ri < 4; ++ri)
          acc[cj][ri] = __builtin_amdgcn_mfma_f32_16x16x32_bf16(wb[cj], xa[ri], acc[cj][ri], 0, 0, 0);
    }
  }
}

// ---------------------------------------------------------------------------
// K1: QKV GEMM, scatter epilogue to Q / K(shifted) / V (all unnormalized).
// ---------------------------------------------------------------------------
__global__ __launch_bounds__(256, 3) void gemm_qkv_mfma(
    const bf16* __restrict__ A, const bf16* __restrict__ Bt,
    bf16* __restrict__ Qo, bf16* __restrict__ Ko, bf16* __restrict__ Vo) {
  __shared__ __align__(16) bf16 As[TSZ];
  __shared__ __align__(16) bf16 Bs[TSZ];
  const int id = blockIdx.x;
  const int sw = (id & 7) * 441 + (id >> 3);   // 3528 = 8 * 441 (bijective)
  const int cti = sw % 18, rti = sw / 18;
  const int ct = cti * 128, rt = rti * 128;
  const int tid = threadIdx.x;
  const int w = tid >> 6, lane = tid & 63;
  const int lr = lane & 15, lg = lane >> 4;
  const int wr = w >> 1, wc = w & 1;

  f32x4 acc[4][4];
  gemm128_core(A, Bt, rt, ct, As, Bs, acc);

  const int s = cti / 6;
#pragma unroll
  for (int ri = 0; ri < 4; ++ri) {
    const int row = rt + wr * 64 + ri * 16 + lr;
    const int b_ = row / NTOK, n = row % NTOK;
    const int t = n / HW, hw = n % HW;
#pragma unroll
    for (int cj = 0; cj < 4; ++cj) {
      const int colb = ct + wc * 64 + cj * 16 + lg * 4;
      const int rem = colb - s * C;
      const int head = rem / HD, chb = rem - head * HD;
      const int bh = b_ * NH + head;
      if (s == 0) {
        uint2 pk;
        pk.x = pk2(acc[cj][ri][0], acc[cj][ri][1]);
        pk.y = pk2(acc[cj][ri][2], acc[cj][ri][3]);
        *(uint2*)(Qo + (size_t)(bh * T + t) * CHW + hw * HD + chb) = pk;
      } else if (s == 1) {
        uint2 pk;
        pk.x = pk2(acc[cj][ri][0], acc[cj][ri][1]);
        pk.y = pk2(acc[cj][ri][2], acc[cj][ri][3]);
        if (t >= 1)
          *(uint2*)(Ko + (size_t)(bh * T + t - 1) * CHW + hw * HD + chb) = pk;
        if (t == T - 1)
          *(uint2*)(Ko + (size_t)(bh * T + t) * CHW + hw * HD + chb) = pk;
      } else {
#pragma unroll
        for (int j = 0; j < 4; ++j)
          Vo[(size_t)(bh * T + t) * CHW + (chb + j) * HW + hw] = f2b(acc[cj][ri][j]);
      }
    }
  }
}

// ---------------------------------------------------------------------------
// K4: proj GEMM + bias -> out f32.
// ---------------------------------------------------------------------------
__global__ __launch_bounds__(256, 3) void gemm_proj_mfma(
    const bf16* __restrict__ A, const bf16* __restrict__ Bt,
    const float* __restrict__ bias, float* __restrict__ out) {
  __shared__ __align__(16) bf16 As[TSZ];
  __shared__ __align__(16) bf16 Bs[TSZ];
  const int id = blockIdx.x;
  const int sw = (id & 7) * 147 + (id >> 3);   // 1176 = 8 * 147 (bijective)
  const int cti = sw % 6, rti = sw / 6;
  const int ct = cti * 128, rt = rti * 128;
  const int tid = threadIdx.x;
  const int w = tid >> 6, lane = tid & 63;
  const int lr = lane & 15, lg = lane >> 4;
  const int wr = w >> 1, wc = w & 1;

  f32x4 acc[4][4];
  gemm128_core(A, Bt, rt, ct, As, Bs, acc);

#pragma unroll
  for (int ri = 0; ri < 4; ++ri) {
    const int row = rt + wr * 64 + ri * 16 + lr;
#pragma unroll
    for (int cj = 0; cj < 4; ++cj) {
      const int colb = ct + wc * 64 + cj * 16 + lg * 4;
      const float4 bv = *(const float4*)(bias + colb);
      float4 o;
      o.x = acc[cj][ri][0] + bv.x;
      o.y = acc[cj][ri][1] + bv.y;
      o.z = acc[cj][ri][2] + bv.z;
      o.w = acc[cj][ri][3] + bv.w;
      *(float4*)(out + (size_t)row * C + colb) = o;
    }
  }
}

// ---------------------------------------------------------------------------
// K3: fused l2norm + corr + appearance + motion attention per bt.
// 1024 threads, 16 waves, one 16-row tile per wave.
// Vt packed sigma layout: slot (kb,lg) = 16 contiguous bytes holding tokens
// {2kb*16+lg*4..+3 | (2kb+1)*16+lg*4..+3} -> single conflict-free b128 read.
// corrT [208][64] XOR block-swizzle; extraction pure stores; pos sweep.
// ---------------------------------------------------------------------------
__global__ __launch_bounds__(1024, 1) void fused_attn(
    const bf16* __restrict__ Qg, const bf16* __restrict__ Kg,
    const bf16* __restrict__ Vg, const float* __restrict__ pos,
    bf16* __restrict__ merged) {
  __shared__ __align__(16) bf16 Klds[208 * KW];    // 43,264 B  K tokens x ch
  __shared__ __align__(16) bf16 Vt[96 * VW3];      // 44,544 B  V^T packed
  __shared__ __align__(16) bf16 corrT[208 * 64];   // 26,624 B  tok x disp(swz)
  __shared__ float invQ[208];                      //     832 B
  const int bt = blockIdx.x;
  const int tid = threadIdx.x;
  const int w = tid >> 6, lane = tid & 63;
  const int lr = lane & 15, lg = lane >> 4;
  const size_t gbase = (size_t)bt * CHW;

  // ---- P0: staging + zero corrT + invQ (4 threads/row) ----
  {
    const uint4* kg = (const uint4*)(Kg + gbase);             // 196 rows x 12
    uint4* kl = (uint4*)Klds;                                 // 13 uint4/row
    for (int i = tid; i < 196 * 12; i += 1024) { const int r = i / 12, g = i - r * 12; kl[r * 13 + g] = kg[i]; }
    const uint4 z4 = make_uint4(0u, 0u, 0u, 0u);
    for (int i = tid; i < 12 * 13; i += 1024) { const int r = 196 + i / 13, g = i % 13; kl[r * 13 + g] = z4; }
    // V staging into packed sigma layout (uint granularity, bit-permuted)
    const uint* vg = (const uint*)(Vg + gbase);               // 96 x 98 u32
    uint* vl = (uint*)Vt;                                     // 116 u32/row
    for (int i = tid; i < 96 * 98; i += 1024) {
      const int c = i / 98, g = i - c * 98;
      const int q = ((g >> 4) << 4) + (((g >> 1) & 3) << 2) + (((g >> 3) & 1) << 1) + (g & 1);
      vl[c * 116 + q] = vg[i];
    }
    for (int i = tid; i < 96 * 14; i += 1024) {               // zero tokens 196..223
      const int c = i / 14, g = 98 + i % 14;
      const int q = ((g >> 4) << 4) + (((g >> 1) & 3) << 2) + (((g >> 3) & 1) << 1) + (g & 1);
      vl[c * 116 + q] = 0u;
    }
    uint4* cz = (uint4*)corrT;                                // 1664 uint4
    for (int i = tid; i < 1664; i += 1024) cz[i] = z4;
    // invQ: 4 threads per row, shfl-reduce
    if (tid < 832) {
      const int row = tid >> 2, sub = tid & 3;
      float s = 0.f;
      if (row < 196) {
        const uint4* qr = (const uint4*)(Qg + gbase + (size_t)row * HD) + sub * 3;
#pragma unroll
        for (int g = 0; g < 3; ++g) {
          const uint4 v = qr[g];
          const uint uu[4] = {v.x, v.y, v.z, v.w};
#pragma unroll
          for (int q = 0; q < 4; ++q) {
            const float a = u2f((ushort)(uu[q] & 0xffff));
            const float b = u2f((ushort)(uu[q] >> 16));
            s += a * a + b * b;
          }
        }
      }
      s += __shfl_xor(s, 1); s += __shfl_xor(s, 2);
      if (sub == 0) invQ[row] = 1.f / fmaxf(sqrtf(s), 1e-12f);
    }
  }
  __syncthreads();
  // ---- P0b: normalize K rows in LDS (4 threads/row) ----
  if (tid < 832) {
    const int row = tid >> 2, sub = tid & 3;
    uint* rowp = (uint*)(Klds + row * KW) + sub * 12;
    float s = 0.f;
#pragma unroll
    for (int g = 0; g < 12; ++g) {
      const uint pk = rowp[g];
      const float a = u2f((ushort)(pk & 0xffff));
      const float b = u2f((ushort)(pk >> 16));
      s += a * a + b * b;
    }
    s += __shfl_xor(s, 1); s += __shfl_xor(s, 2);
    const float inv = 1.f / fmaxf(sqrtf(s), 1e-12f);
#pragma unroll
    for (int g = 0; g < 12; ++g) {
      const uint pk = rowp[g];
      rowp[g] = pk2(u2f((ushort)(pk & 0xffff)) * inv, u2f((ushort)(pk >> 16)) * inv);
    }
  }
  __syncthreads();

  const int b_ = bt >> 6, head = (bt >> 3) & 7, tt = bt & 7;
  union PW { short8v v; uint u[4]; };
  const int rt = w;                       // one tile per wave
  f32x4 pacc[6];
#pragma unroll
  for (int ct = 0; ct < 6; ++ct) pacc[ct] = (f32x4){0.f, 0.f, 0.f, 0.f};

  // ---- P1: S^T -> scale by invQ -> corr store -> softmax -> app PV ----
  if (rt < NT) {
    const int rq = (rt * 16 + lr > 195) ? 195 : rt * 16 + lr;
    short8v qf[3];
#pragma unroll
    for (int kc = 0; kc < 3; ++kc)
      qf[kc] = *(const short8v*)(Qg + gbase + (size_t)rq * HD + kc * 32 + lg * 8);
    f32x4 sacc[NT];
#pragma unroll
    for (int mt = 0; mt < NT; ++mt) sacc[mt] = (f32x4){0.f, 0.f, 0.f, 0.f};
    __builtin_amdgcn_s_setprio(1);
#pragma unroll
    for (int kc = 0; kc < 3; ++kc)
#pragma unroll
      for (int mt = 0; mt < NT; ++mt) {
        const short8v kf = *(const short8v*)&Klds[(mt * 16 + lr) * KW + kc * 32 + lg * 8];
        sacc[mt] = __builtin_amdgcn_mfma_f32_16x16x32_bf16(kf, qf[kc], sacc[mt], 0, 0, 0);
      }
    __builtin_amdgcn_s_setprio(0);
    // apply Q normalization (lane-constant: query = rq)
    const float iq = invQ[rq];
#pragma unroll
    for (int mt = 0; mt < NT; ++mt) {
      sacc[mt][0] *= iq; sacc[mt][1] *= iq; sacc[mt][2] *= iq; sacc[mt][3] *= iq;
    }
    // corr extraction: PURE STORES of S into swizzled corrT (pos added later)
    const int rowg = rt * 16 + lr;
    if (rowg < 196) {
      const int h = rowg / 14, wq = rowg - (rowg / 14) * 14;
      bf16* crow = corrT + rowg * 64;
      const int rsw = rowg & 7;
      int h2 = 0, w2 = lg * 4;
#pragma unroll
      for (int mt = 0; mt < NT; ++mt) {
        int hh = h2, ww = w2;
#pragma unroll
        for (int r = 0; r < 4; ++r) {
          if (mt < 12 || lg * 4 + r < 4) {
            const int dh = hh - h + 3, dw = ww - wq + 3;
            if (((unsigned)dh < 7u) && ((unsigned)dw < 7u)) {
              const int u = dh * 7 + dw;
              crow[(((u >> 3) ^ rsw) << 3) + (u & 7)] = f2b(sacc[mt][r]);
            }
          }
          if (++ww == 14) { ww = 0; ++hh; }
        }
        w2 += 2; h2 += 1; if (w2 >= 14) { w2 -= 14; h2 += 1; }
      }
    }
    // softmax over keys (0.5 folded)
    float m0 = -1e30f, m1 = -1e30f, m2 = -1e30f, m3 = -1e30f;
#pragma unroll
    for (int mt = 0; mt < 12; ++mt) {
      m0 = fmaxf(m0, sacc[mt][0]); m1 = fmaxf(m1, sacc[mt][1]);
      m2 = fmaxf(m2, sacc[mt][2]); m3 = fmaxf(m3, sacc[mt][3]);
    }
    if (lg == 0) {
      m0 = fmaxf(m0, sacc[12][0]); m1 = fmaxf(m1, sacc[12][1]);
      m2 = fmaxf(m2, sacc[12][2]); m3 = fmaxf(m3, sacc[12][3]);
    }
    float mx = fmaxf(fmaxf(m0, m1), fmaxf(m2, m3));
    mx = fmaxf(mx, __shfl_xor(mx, 16));
    mx = fmaxf(mx, __shfl_xor(mx, 32));
    float s0 = 0.f, s1 = 0.f, s2 = 0.f, s3 = 0.f;
#pragma unroll
    for (int mt = 0; mt < NT; ++mt) {
      const bool dead = (mt == 12) && (lg != 0);
      const float e0 = dead ? 0.f : __expf(sacc[mt][0] - mx);
      const float e1 = dead ? 0.f : __expf(sacc[mt][1] - mx);
      const float e2 = dead ? 0.f : __expf(sacc[mt][2] - mx);
      const float e3 = dead ? 0.f : __expf(sacc[mt][3] - mx);
      sacc[mt][0] = e0; sacc[mt][1] = e1; sacc[mt][2] = e2; sacc[mt][3] = e3;
      s0 += e0; s1 += e1; s2 += e2; s3 += e3;
    }
    float s = (s0 + s1) + (s2 + s3);
    s += __shfl_xor(s, 16); s += __shfl_xor(s, 32);
    const float sc = 0.5f / s;
    PW pf[7];
#pragma unroll
    for (int kb = 0; kb < 7; ++kb) {
      pf[kb].u[0] = pk2(sacc[2 * kb][0] * sc, sacc[2 * kb][1] * sc);
      pf[kb].u[1] = pk2(sacc[2 * kb][2] * sc, sacc[2 * kb][3] * sc);
      if (kb < 6) {
        pf[kb].u[2] = pk2(sacc[2 * kb + 1][0] * sc, sacc[2 * kb + 1][1] * sc);
        pf[kb].u[3] = pk2(sacc[2 * kb + 1][2] * sc, sacc[2 * kb + 1][3] * sc);
      } else { pf[kb].u[2] = 0u; pf[kb].u[3] = 0u; }
    }
    __builtin_amdgcn_s_setprio(1);
#pragma unroll
    for (int ct = 0; ct < 6; ++ct) {
      const int c = ct * 16 + lr;
#pragma unroll
      for (int kb = 0; kb < 7; ++kb) {
        const short8v vf = *(const short8v*)&Vt[c * VW3 + kb * 32 + lg * 8];
        pacc[ct] = __builtin_amdgcn_mfma_f32_16x16x32_bf16(pf[kb].v, vf, pacc[ct], 0, 0, 0);
      }
    }
    __builtin_amdgcn_s_setprio(0);
  }
  __syncthreads();

  // ---- pos sweep: corrT += pos (parallel, coalesced) ----
  {
    uint* ct32 = (uint*)corrT;
    for (int i = tid; i < 208 * 25; i += 1024) {
      const int n = i % 208, wp = i / 208;   // wp in [0,25): u0=2wp<=48
      if (n < 196) {
        const int u0 = 2 * wp, u1 = u0 + 1;
        const int ad = n * 32 + (((wp >> 2) ^ (n & 7)) << 2) + (wp & 3);
        const uint pk = ct32[ad];
        const float v0 = u2f((ushort)(pk & 0xffff)) + pos[u0 * 196 + n];
        const float v1 = u2f((ushort)(pk >> 16)) + (u1 < 49 ? pos[u1 * 196 + n] : 0.f);
        ct32[ad] = pk2(v0, v1);
      }
    }
  }
  __syncthreads();

  // ---- P2: M = corrT.corrT^T -> softmax -> PV (+= into pacc) -> store ----
  if (rt < NT) {
    const int csw = lr & 7;
    short8v cq[2];
#pragma unroll
    for (int kc = 0; kc < 2; ++kc)
      cq[kc] = *(const short8v*)&corrT[(rt * 16 + lr) * 64 + (((kc * 4 + lg) ^ csw) << 3)];
    f32x4 macc[NT];
#pragma unroll
    for (int mt = 0; mt < NT; ++mt) macc[mt] = (f32x4){0.f, 0.f, 0.f, 0.f};
    __builtin_amdgcn_s_setprio(1);
#pragma unroll
    for (int kc = 0; kc < 2; ++kc)
#pragma unroll
      for (int mt = 0; mt < NT; ++mt) {
        const short8v ca = *(const short8v*)&corrT[(mt * 16 + lr) * 64 + (((kc * 4 + lg) ^ csw) << 3)];
        macc[mt] = __builtin_amdgcn_mfma_f32_16x16x32_bf16(ca, cq[kc], macc[mt], 0, 0, 0);
      }
    __builtin_amdgcn_s_setprio(0);
    float m0 = -1e30f, m1 = -1e30f, m2 = -1e30f, m3 = -1e30f;
#pragma unroll
    for (int mt = 0; mt < 12; ++mt) {
      m0 = fmaxf(m0, macc[mt][0]); m1 = fmaxf(m1, macc[mt][1]);
      m2 = fmaxf(m2, macc[mt][2]); m3 = fmaxf(m3, macc[mt][3]);
    }
    if (lg == 0) {
      m0 = fmaxf(m0, macc[12][0]); m1 = fmaxf(m1, macc[12][1]);
      m2 = fmaxf(m2, macc[12][2]); m3 = fmaxf(m3, macc[12][3]);
    }
    float mx = fmaxf(fmaxf(m0, m1), fmaxf(m2, m3));
    mx = fmaxf(mx, __shfl_xor(mx, 16));
    mx = fmaxf(mx, __shfl_xor(mx, 32));
    float s0 = 0.f, s1 = 0.f, s2 = 0.f, s3 = 0.f;
#pragma unroll
    for (int mt = 0; mt < NT; ++mt) {
      const bool dead = (mt == 12) && (lg != 0);
      const float e0 = dead ? 0.f : __expf(macc[mt][0] - mx);
      const float e1 = dead ? 0.f : __expf(macc[mt][1] - mx);
      const float e2 = dead ? 0.f : __expf(macc[mt][2] - mx);
      const float e3 = dead ? 0.f : __expf(macc[mt][3] - mx);
      macc[mt][0] = e0; macc[mt][1] = e1; macc[mt][2] = e2; macc[mt][3] = e3;
      s0 += e0; s1 += e1; s2 += e2; s3 += e3;
    }
    float s = (s0 + s1) + (s2 + s3);
    s += __shfl_xor(s, 16); s += __shfl_xor(s, 32);
    const float sc = 0.5f / s;
    PW pf[7];
#pragma unroll
    for (int kb = 0; kb < 7; ++kb) {
      pf[kb].u[0] = pk2(macc[2 * kb][0] * sc, macc[2 * kb][1] * sc);
      pf[kb].u[1] = pk2(macc[2 * kb][2] * sc, macc[2 * kb][3] * sc);
      if (kb < 6) {
        pf[kb].u[2] = pk2(macc[2 * kb + 1][0] * sc, macc[2 * kb + 1][1] * sc);
        pf[kb].u[3] = pk2(macc[2 * kb + 1][2] * sc, macc[2 * kb + 1][3] * sc);
      } else { pf[kb].u[2] = 0u; pf[kb].u[3] = 0u; }
    }
    __builtin_amdgcn_s_setprio(1);
#pragma unroll
    for (int ct = 0; ct < 6; ++ct) {
      const int c = ct * 16 + lr;
#pragma unroll
      for (int kb = 0; kb < 7; ++kb) {
        const short8v vf = *(const short8v*)&Vt[c * VW3 + kb * 32 + lg * 8];
        pacc[ct] = __builtin_amdgcn_mfma_f32_16x16x32_bf16(pf[kb].v, vf, pacc[ct], 0, 0, 0);
      }
    }
    __builtin_amdgcn_s_setprio(0);
    // single merged store: 0.5*(app+motion)
#pragma unroll
    for (int r = 0; r < 4; ++r) {
      const int rowq = rt * 16 + lg * 4 + r;
      if (rowq < 196) {
        const size_t ob = ((size_t)(b_ * NTOK + tt * HW + rowq)) * C + head * HD;
#pragma unroll
        for (int ct = 0; ct < 6; ++ct)
          merged[ob + ct * 16 + lr] = f2b(pacc[ct][r]);
      }
    }
  }
}

}  // namespace

extern "C" void kernel_launch(void* const* d_in, const int* in_sizes, int n_in,
                              void* d_out, int out_size, void* d_ws, size_t ws_size,
                              hipStream_t stream) {
  (void)in_sizes; (void)n_in; (void)out_size; (void)ws_size;
  const float* x      = (const float*)d_in[0];
  const float* w_qkv  = (const float*)d_in[1];
  const float* w_proj = (const float*)d_in[2];
  const float* b_proj = (const float*)d_in[3];
  const float* pos    = (const float*)d_in[4];
  float* out = (float*)d_out;

  char* p = (char*)d_ws;
  bf16* Qb = (bf16*)p;      p += (size_t)BHT * CHW * sizeof(bf16);    // 38.5 MB
  bf16* Kb = (bf16*)p;      p += (size_t)BHT * CHW * sizeof(bf16);    // 38.5 MB
  bf16* Vb = (bf16*)p;      p += (size_t)BHT * CHW * sizeof(bf16);    // 38.5 MB
  bf16* xbm = (bf16*)p;     p += (size_t)NROWS * C * sizeof(bf16);    // 38.5 MB (xb, then merged)
  bf16* wqkvT = (bf16*)p;   p += (size_t)C3 * C * sizeof(bf16);       // 3.5 MB
  bf16* wprojT = (bf16*)p;  p += (size_t)C * C * sizeof(bf16);        // 1.2 MB
  // total ws: ~159 MB

  prep<<<9984, 256, 0, stream>>>(x, xbm, w_qkv, wqkvT, w_proj, wprojT);
  gemm_qkv_mfma<<<3528, 256, 0, stream>>>(xbm, wqkvT, Qb, Kb, Vb);
  fused_attn<<<BHT, 1024, 0, stream>>>(Qb, Kb, Vb, pos, xbm /*merged*/);
  gemm_proj_mfma<<<1176, 256, 0, stream>>>(xbm, wprojT, b_proj, out);
}